// Round 5
// baseline (401.898 us; speedup 1.0000x reference)
//
#include <hip/hip_runtime.h>
#include <hip/hip_bf16.h>

typedef __hip_bfloat16 bf16;
typedef float floatx4 __attribute__((ext_vector_type(4)));
typedef short bf16x8 __attribute__((ext_vector_type(8)));

#define B_      2
#define S_      2048
#define IN_     512
#define E_      1024
#define INNER_  2048
#define NH_     4
#define DH_     512
#define T_      (B_*S_)      // 4096 tokens
#define EPS_CELL 1e-6f
#define LN_EPS_  1e-5f
#define LS      72           // padded LDS row stride (shorts) for non-async kernels
#define CTB_    4            // tokens per block in conv_headwise

__device__ inline float b2f(bf16 x){ return __bfloat162float(x); }
__device__ inline bf16  f2b(float x){ return __float2bfloat16(x); }
__device__ inline float us2f(unsigned short u){ union{unsigned int i; float f;} v; v.i = ((unsigned int)u)<<16; return v.f; }
__device__ inline float u2f(unsigned int u){ union{unsigned int i; float f;} v; v.i = u; return v.f; }
__device__ inline unsigned short f2bu(float x){ bf16 t = __float2bfloat16(x); unsigned short r; __builtin_memcpy(&r,&t,2); return r; }
__device__ inline void unpack8(uint4 u, float* f){
  f[0]=u2f(u.x<<16); f[1]=u2f(u.x&0xffff0000u);
  f[2]=u2f(u.y<<16); f[3]=u2f(u.y&0xffff0000u);
  f[4]=u2f(u.z<<16); f[5]=u2f(u.z&0xffff0000u);
  f[6]=u2f(u.w<<16); f[7]=u2f(u.w&0xffff0000u);
}
__device__ inline uint4 pack8(const float* f){
  uint4 u;
  u.x = (unsigned)f2bu(f[0]) | ((unsigned)f2bu(f[1])<<16);
  u.y = (unsigned)f2bu(f[2]) | ((unsigned)f2bu(f[3])<<16);
  u.z = (unsigned)f2bu(f[4]) | ((unsigned)f2bu(f[5])<<16);
  u.w = (unsigned)f2bu(f[6]) | ((unsigned)f2bu(f[7])<<16);
  return u;
}
__device__ inline void stv(bf16* p, float v){ *p = f2b(v); }
__device__ inline void stv(float* p, float v){ *p = v; }

// ---- async 16B global->LDS copy (wave-uniform base + lane*16 pattern) ----
typedef __attribute__((address_space(3))) unsigned int lds_u32_t;
typedef __attribute__((address_space(1))) const unsigned int glb_u32_t;
__device__ __forceinline__ void cp_async16(const bf16* g, short* l){
  __builtin_amdgcn_global_load_lds((glb_u32_t*)(const void*)g,
                                   (lds_u32_t*)(void*)l, 16, 0, 0);
}
// swizzled LDS offset (shorts) for Nx64 tile: row-dense, chunk XOR row&7
__device__ __forceinline__ int so_(int row, int c8){ return row*64 + (((c8) ^ (row&7))<<3); }
// epilogue repack offset for Nx128-short tile: chunk XOR row&15
__device__ __forceinline__ int eo_(int row, int ch){ return row*128 + (((ch) ^ (row&15))<<3); }

// stage rows of a {64,128}x64-short tile (row stride `stride` in global)
#define STAGE_ASYNC(dst, srcbase, stride, kk) \
  { int slot_ = (kk)*256 + tid; int r_ = slot_>>3; int c8_ = (slot_&7) ^ (r_&7); \
    cp_async16((srcbase) + (size_t)r_*(stride) + c8_*8, &dst[slot_*8]); }

// ---------------- fp32 -> bf16 elementwise convert ----------------
__global__ __launch_bounds__(256) void convert_bf16(const float* __restrict__ X,
    bf16* __restrict__ Y, int n8){
  int i = blockIdx.x*256 + threadIdx.x;
  if (i >= n8) return;
  const float4* p = (const float4*)(X) + i*2;
  float4 a = p[0], b = p[1];
  ushort4 o0, o1;
  o0.x=f2bu(a.x); o0.y=f2bu(a.y); o0.z=f2bu(a.z); o0.w=f2bu(a.w);
  o1.x=f2bu(b.x); o1.y=f2bu(b.y); o1.z=f2bu(b.z); o1.w=f2bu(b.w);
  ushort4* q = (ushort4*)(Y) + i*2;
  q[0]=o0; q[1]=o1;
}

// ---------------- W[K,N] fp32 -> Wt[N,K] bf16 (64x64 LDS tiles) ----------------
__global__ __launch_bounds__(256) void transpose_conv_w(const float* __restrict__ W,
    bf16* __restrict__ Wt, int K, int N){
  int n0 = blockIdx.x*64, k0 = blockIdx.y*64;
  __shared__ float tl[64][65];
  int tid = threadIdx.x;
  #pragma unroll
  for (int i=0;i<4;i++){
    int idx = tid + i*256; int r = idx>>4, c4 = idx&15;
    float4 v = *(const float4*)(W + (size_t)(k0+r)*N + n0 + c4*4);
    tl[r][c4*4+0]=v.x; tl[r][c4*4+1]=v.y; tl[r][c4*4+2]=v.z; tl[r][c4*4+3]=v.w;
  }
  __syncthreads();
  #pragma unroll
  for (int i=0;i<4;i++){
    int idx = tid + i*256; int rn = idx>>4, c4 = idx&15;
    ushort4 o;
    o.x=f2bu(tl[c4*4+0][rn]); o.y=f2bu(tl[c4*4+1][rn]);
    o.z=f2bu(tl[c4*4+2][rn]); o.w=f2bu(tl[c4*4+3][rn]);
    *(ushort4*)(Wt + (size_t)(n0+rn)*K + k0 + c4*4) = o;
  }
}

// ---------------- MFMA GEMM: C[M,N] = A[M,K] @ Bt[N,K]^T + bias ----------------
// 1-D grid MM*NN; per-XCD m-stripe swizzle. Double-buffered LDS K-tiles:
// stage of tile t+1 issued BEFORE compute of tile t; one __syncthreads per tile.
__global__ __launch_bounds__(256) void mfma_gemm(const bf16* __restrict__ A,
    const bf16* __restrict__ Bt, const float* __restrict__ bias, bf16* __restrict__ C,
    int Kd, int lda, int ldc, int NN){
  int bid = blockIdx.x;
  int MM = gridDim.x / NN;
  int mPerX = MM >> 3;
  int xcd = bid & 7, seq = bid >> 3;
  int nb = seq % NN, mb = xcd*mPerX + seq / NN;
  int n0 = nb*128, m0 = mb*128;
  __shared__ __align__(16) short smem[32768];   // 2 slots x (A 8192 | B 8192); reused for C repack
  int tid = threadIdx.x;
  int w = tid>>6, l = tid&63, lq = l>>4, lr = l&15;
  int wm = (w>>1)*64, wn = (w&1)*64;
  const bf16* Abase = A + (size_t)m0*lda;
  const bf16* Bbase = Bt + (size_t)n0*Kd;
  floatx4 acc[4][4];
  #pragma unroll
  for (int mi=0;mi<4;mi++){
    #pragma unroll
    for (int ni=0;ni<4;ni++) acc[mi][ni] = (floatx4){0.f,0.f,0.f,0.f};
  }
  short* As0 = smem;          short* Bs0 = smem + 8192;
  short* As1 = smem + 16384;  short* Bs1 = smem + 24576;
  int NT = Kd >> 6;
  // prologue: stage tile 0 into slot 0
  #pragma unroll
  for (int kk=0;kk<4;kk++){
    STAGE_ASYNC(As0, Abase, lda, kk);
    STAGE_ASYNC(Bs0, Bbase, Kd, kk);
  }
  __syncthreads();
  for (int t=0; t<NT; ++t){
    short* As  = (t&1) ? As1 : As0;
    short* Bs  = (t&1) ? Bs1 : Bs0;
    short* Asn = (t&1) ? As0 : As1;
    short* Bsn = (t&1) ? Bs0 : Bs1;
    if (t+1 < NT){
      int k0 = (t+1)*64;
      #pragma unroll
      for (int kk=0;kk<4;kk++){
        STAGE_ASYNC(Asn, Abase + k0, lda, kk);
        STAGE_ASYNC(Bsn, Bbase + k0, Kd, kk);
      }
    }
    #pragma unroll
    for (int ks=0; ks<2; ks++){
      bf16x8 af[4], bfr[4];
      #pragma unroll
      for (int mi=0;mi<4;mi++) af[mi] = *(const bf16x8*)&As[so_(wm+mi*16+lr, ks*4+lq)];
      #pragma unroll
      for (int ni=0;ni<4;ni++) bfr[ni] = *(const bf16x8*)&Bs[so_(wn+ni*16+lr, ks*4+lq)];
      #pragma unroll
      for (int mi=0;mi<4;mi++){
        #pragma unroll
        for (int ni=0;ni<4;ni++)
          acc[mi][ni] = __builtin_amdgcn_mfma_f32_16x16x32_bf16(af[mi], bfr[ni], acc[mi][ni], 0,0,0);
      }
    }
    __syncthreads();   // drains vmcnt: tile t+1 landed; all waves done reading slot t
  }
  float bb[4];
  #pragma unroll
  for (int ni=0;ni<4;ni++) bb[ni] = bias[n0 + wn + ni*16 + lr];
  #pragma unroll
  for (int mi=0;mi<4;mi++){
    #pragma unroll
    for (int ni=0;ni<4;ni++){
      int coll = wn + ni*16 + lr;
      int ch = coll>>3, off = coll&7;
      #pragma unroll
      for (int r=0;r<4;r++){
        int rowl = wm + mi*16 + lq*4 + r;
        smem[rowl*128 + (((ch) ^ (rowl&15))<<3) + off] = (short)f2bu(acc[mi][ni][r] + bb[ni]);
      }
    }
  }
  __syncthreads();
  #pragma unroll
  for (int i=0;i<8;i++){
    int slot = i*256 + tid;
    int r = slot >> 4, c8 = slot & 15;
    uint4 val = *(const uint4*)&smem[eo_(r, c8)];
    *(uint4*)(C + (size_t)(m0+r)*ldc + n0 + c8*8) = val;
  }
}

// ---------------- layernorm over rows of length E_ (opt. fused add) ----------------
template<typename OutT>
__global__ __launch_bounds__(256) void ln_rows(const bf16* __restrict__ X,
    const bf16* __restrict__ Xadd, const float* __restrict__ w, OutT* __restrict__ Y){
  int row = blockIdx.x, tid = threadIdx.x;
  size_t base = (size_t)row*E_;
  float vals[4], s=0.f, s2=0.f;
  #pragma unroll
  for (int e=0;e<4;e++){
    int c = e*256+tid;
    float v = b2f(X[base+c]);
    if (Xadd) v += b2f(Xadd[base+c]);
    vals[e]=v; s+=v; s2+=v*v;
  }
  __shared__ float sa[256], sb[256];
  sa[tid]=s; sb[tid]=s2; __syncthreads();
  for (int off=128; off>0; off>>=1){
    if (tid<off){ sa[tid]+=sa[tid+off]; sb[tid]+=sb[tid+off]; }
    __syncthreads();
  }
  float mean = sa[0]*(1.f/E_);
  float var  = sb[0]*(1.f/E_) - mean*mean;
  float rstd = rsqrtf(var + LN_EPS_);
  #pragma unroll
  for (int e=0;e<4;e++){
    int c = e*256+tid;
    stv(&Y[base+c], (vals[e]-mean)*rstd*w[c]);
  }
}

// ---------------- fused causal conv(K=4)+SiLU and block-diagonal q/k/v ----------------
// block = CTB_ tokens x all 2048 channels; thread = 8 channels (2 quads) x 4 tokens.
__global__ __launch_bounds__(256) void conv_headwise(const bf16* __restrict__ up,
    const float* __restrict__ cw, const float* __restrict__ cb,
    const float* __restrict__ qw, const float* __restrict__ qb,
    const float* __restrict__ kw, const float* __restrict__ kb,
    const float* __restrict__ vw, const float* __restrict__ vb,
    bf16* __restrict__ xca, bf16* __restrict__ q, bf16* __restrict__ k,
    bf16* __restrict__ v){
  int t0 = blockIdx.x*CTB_;          // first global token of block
  int s0 = t0 & (S_-1);              // position within sequence
  int c0 = threadIdx.x*8;            // channel base (2 quads)
  int hw0 = c0 >> 2;                 // first headwise-block index

  // sliding tap window: rows t0-3 .. t0+3 (7 rows of 8 channels)
  float row[7][8];
  #pragma unroll
  for (int j=0;j<7;j++){
    if (s0-3+j >= 0){
      uint4 rv = *(const uint4*)(up + (size_t)(t0-3+j)*(2*INNER_) + c0);
      unpack8(rv, row[j]);
    } else {
      #pragma unroll
      for (int e=0;e<8;e++) row[j][e]=0.f;
    }
  }

  // ---- causal conv + SiLU -> xc, store xca ----
  float xc[CTB_][8];
  {
    float cwv[8][4], cbv[8];
    #pragma unroll
    for (int e=0;e<8;e++){
      float4 w4 = *(const float4*)(cw + (size_t)(c0+e)*4);
      cwv[e][0]=w4.x; cwv[e][1]=w4.y; cwv[e][2]=w4.z; cwv[e][3]=w4.w;
    }
    float4 b0 = *(const float4*)(cb+c0), b1 = *(const float4*)(cb+c0+4);
    cbv[0]=b0.x; cbv[1]=b0.y; cbv[2]=b0.z; cbv[3]=b0.w;
    cbv[4]=b1.x; cbv[5]=b1.y; cbv[6]=b1.z; cbv[7]=b1.w;
    #pragma unroll
    for (int i=0;i<CTB_;i++){
      #pragma unroll
      for (int e=0;e<8;e++){
        float a = cbv[e];
        #pragma unroll
        for (int t=0;t<4;t++) a += row[i+t][e]*cwv[e][t];
        xc[i][e] = a/(1.f+expf(-a));
      }
      *(uint4*)(xca + (size_t)(t0+i)*INNER_ + c0) = pack8(xc[i]);
    }
  }

  // ---- v projection from x_m = row[i+3] ----
  {
    float wv_[32], bv[8];
    #pragma unroll
    for (int g=0;g<2;g++){
      #pragma unroll
      for (int r4=0;r4<4;r4++){
        float4 w4 = *(const float4*)(vw + (size_t)(hw0+g)*16 + r4*4);
        wv_[g*16+r4*4+0]=w4.x; wv_[g*16+r4*4+1]=w4.y;
        wv_[g*16+r4*4+2]=w4.z; wv_[g*16+r4*4+3]=w4.w;
      }
    }
    float4 b0 = *(const float4*)(vb+c0), b1 = *(const float4*)(vb+c0+4);
    bv[0]=b0.x; bv[1]=b0.y; bv[2]=b0.z; bv[3]=b0.w;
    bv[4]=b1.x; bv[5]=b1.y; bv[6]=b1.z; bv[7]=b1.w;
    #pragma unroll
    for (int i=0;i<CTB_;i++){
      float ov[8];
      #pragma unroll
      for (int g=0;g<2;g++){
        #pragma unroll
        for (int o=0;o<4;o++){
          float a = bv[g*4+o];
          #pragma unroll
          for (int d=0;d<4;d++) a += row[i+3][g*4+d]*wv_[g*16+o*4+d];
          ov[g*4+o]=a;
        }
      }
      *(uint4*)(v + (size_t)(t0+i)*INNER_ + c0) = pack8(ov);
    }
  }

  // ---- q projection from xc ----
  {
    float wv_[32], bv[8];
    #pragma unroll
    for (int g=0;g<2;g++){
      #pragma unroll
      for (int r4=0;r4<4;r4++){
        float4 w4 = *(const float4*)(qw + (size_t)(hw0+g)*16 + r4*4);
        wv_[g*16+r4*4+0]=w4.x; wv_[g*16+r4*4+1]=w4.y;
        wv_[g*16+r4*4+2]=w4.z; wv_[g*16+r4*4+3]=w4.w;
      }
    }
    float4 b0 = *(const float4*)(qb+c0), b1 = *(const float4*)(qb+c0+4);
    bv[0]=b0.x; bv[1]=b0.y; bv[2]=b0.z; bv[3]=b0.w;
    bv[4]=b1.x; bv[5]=b1.y; bv[6]=b1.z; bv[7]=b1.w;
    #pragma unroll
    for (int i=0;i<CTB_;i++){
      float ov[8];
      #pragma unroll
      for (int g=0;g<2;g++){
        #pragma unroll
        for (int o=0;o<4;o++){
          float a = bv[g*4+o];
          #pragma unroll
          for (int d=0;d<4;d++) a += xc[i][g*4+d]*wv_[g*16+o*4+d];
          ov[g*4+o]=a;
        }
      }
      *(uint4*)(q + (size_t)(t0+i)*INNER_ + c0) = pack8(ov);
    }
  }

  // ---- k projection from xc ----
  {
    float wv_[32], bv[8];
    #pragma unroll
    for (int g=0;g<2;g++){
      #pragma unroll
      for (int r4=0;r4<4;r4++){
        float4 w4 = *(const float4*)(kw + (size_t)(hw0+g)*16 + r4*4);
        wv_[g*16+r4*4+0]=w4.x; wv_[g*16+r4*4+1]=w4.y;
        wv_[g*16+r4*4+2]=w4.z; wv_[g*16+r4*4+3]=w4.w;
      }
    }
    float4 b0 = *(const float4*)(kb+c0), b1 = *(const float4*)(kb+c0+4);
    bv[0]=b0.x; bv[1]=b0.y; bv[2]=b0.z; bv[3]=b0.w;
    bv[4]=b1.x; bv[5]=b1.y; bv[6]=b1.z; bv[7]=b1.w;
    #pragma unroll
    for (int i=0;i<CTB_;i++){
      float ov[8];
      #pragma unroll
      for (int g=0;g<2;g++){
        #pragma unroll
        for (int o=0;o<4;o++){
          float a = bv[g*4+o];
          #pragma unroll
          for (int d=0;d<4;d++) a += xc[i][g*4+d]*wv_[g*16+o*4+d];
          ov[g*4+o]=a;
        }
      }
      *(uint4*)(k + (size_t)(t0+i)*INNER_ + c0) = pack8(ov);
    }
  }
}

// ---------------- pack ig_w/fg_w into lane-coalesced bf16 layout ----------------
__global__ __launch_bounds__(256) void pack_gates_w(const float* __restrict__ igw,
    const float* __restrict__ fgw, bf16* __restrict__ gwb){
  int idx = blockIdx.x*256 + threadIdx.x;
  if (idx >= 3*INNER_) return;
  int g = idx >> 9;
  int e = (idx >> 6) & 7;
  int l = idx & 63;
  int r = g*512 + l*8 + e;
  float4 a = *(const float4*)(igw + (size_t)r*4);
  float4 b = *(const float4*)(fgw + (size_t)r*4);
  ushort4 o0, o1;
  o0.x=f2bu(a.x); o0.y=f2bu(a.y); o0.z=f2bu(a.z); o0.w=f2bu(a.w);
  o1.x=f2bu(b.x); o1.y=f2bu(b.y); o1.z=f2bu(b.z); o1.w=f2bu(b.w);
  *(ushort4*)(gwb + (size_t)idx*8)     = o0;
  *(ushort4*)(gwb + (size_t)idx*8 + 4) = o1;
}

// ---------------- ig/fg gates: register-resident GEMV ----------------
__global__ __launch_bounds__(256) void gates_kernel(const bf16* __restrict__ q,
    const bf16* __restrict__ k, const bf16* __restrict__ v,
    const bf16* __restrict__ gwb, const float* __restrict__ igb,
    const float* __restrict__ fgb, float* __restrict__ igo, float* __restrict__ fgo){
  __shared__ float red[4*32];
  int tid = threadIdx.x;
  int w = tid >> 6, l = tid & 63;
  int quad = w >> 1, kh = w & 1;
  int tok0 = blockIdx.x*8 + quad*4;
  float acc[4][8];
  #pragma unroll
  for (int t=0;t<4;t++){
    #pragma unroll
    for (int n=0;n<8;n++) acc[t][n]=0.f;
  }
  #pragma unroll 2
  for (int it=0; it<6; ++it){
    int src = it >> 1, j = it & 1;
    const bf16* sp = (src==0) ? q : ((src==1) ? k : v);
    int pos = kh*1024 + j*512 + l*8;        // channel within src
    int g = src*4 + kh*2 + j;               // 512-row weight group
    uint4 dv[4];
    #pragma unroll
    for (int t=0;t<4;t++)
      dv[t] = *(const uint4*)(sp + (size_t)(tok0+t)*INNER_ + pos);
    float d[4][8];
    #pragma unroll
    for (int t=0;t<4;t++) unpack8(dv[t], d[t]);
    const bf16* wb = gwb + (size_t)g*512*8;
    #pragma unroll
    for (int e=0;e<8;e++){
      uint4 wv = *(const uint4*)(wb + (size_t)(e*64 + l)*8);
      float w8[8]; unpack8(wv, w8);
      #pragma unroll
      for (int t=0;t<4;t++){
        #pragma unroll
        for (int n=0;n<8;n++) acc[t][n] += d[t][e]*w8[n];
      }
    }
  }
  // butterfly over 64 lanes
  #pragma unroll
  for (int off=1; off<64; off<<=1){
    #pragma unroll
    for (int t=0;t<4;t++){
      #pragma unroll
      for (int n=0;n<8;n++) acc[t][n] += __shfl_xor(acc[t][n], off);
    }
  }
  if (l == 0){
    #pragma unroll
    for (int t=0;t<4;t++){
      #pragma unroll
      for (int n=0;n<8;n++) red[w*32 + t*8 + n] = acc[t][n];
    }
  }
  __syncthreads();
  if (tid < 64){
    int qd = tid >> 5, tn = tid & 31;
    int t = tn >> 3, n = tn & 7;
    float val = red[(qd*2)*32 + tn] + red[(qd*2+1)*32 + tn];
    int tok = blockIdx.x*8 + qd*4 + t;
    int b = tok >> 11, s = tok & (S_-1);
    if (n < 4) igo[((size_t)(b*NH_+n))*S_ + s] = val + igb[n];
    else       fgo[((size_t)(b*NH_+(n-4)))*S_ + s] = val + fgb[n-4];
  }
}

// ---------------- per-head scan: F=cumsum(logsigmoid(fg)); a=ig-F; M=prefmax(a) ----
__global__ __launch_bounds__(256) void scan8(const float* __restrict__ igp,
    const float* __restrict__ fgp, float* __restrict__ ap,
    float* __restrict__ Mp, float* __restrict__ flp, float* __restrict__ rowsum){
  int h = blockIdx.x, tid = threadIdx.x;
  const float* fg = fgp + (size_t)h*S_;
  const float* ig = igp + (size_t)h*S_;
  int base = tid*8;
  float loc[8], run = 0.f;
  #pragma unroll
  for (int e=0;e<8;e++){
    float x = fg[base+e];
    float ls = fminf(x,0.f) - log1pf(expf(-fabsf(x)));
    run += ls; loc[e] = run;
  }
  __shared__ float sd[256];
  sd[tid]=run; __syncthreads();
  if (tid==0){ float r=0.f; for(int t=0;t<256;t++){ float t0=sd[t]; sd[t]=r; r+=t0; } }
  __syncthreads();
  float off = sd[tid];
  float lm[8], rm = -3e38f;
  #pragma unroll
  for (int e=0;e<8;e++){
    float F = loc[e]+off; loc[e]=F;
    float aj = ig[base+e]-F;
    ap[(size_t)h*S_+base+e]=aj;
    rm = fmaxf(rm, aj); lm[e]=rm;
  }
  __syncthreads();
  sd[tid]=rm; __syncthreads();
  if (tid==0){ float r=-3e38f; for(int t=0;t<256;t++){ float t0=sd[t]; sd[t]=r; r=fmaxf(r,t0); } }
  __syncthreads();
  float offm = sd[tid];
  #pragma unroll
  for (int e=0;e<8;e++){
    float M = fmaxf(lm[e], offm);
    Mp[(size_t)h*S_+base+e]=M;
    flp[(size_t)h*S_+base+e]=expf(-loc[e]-M);
    rowsum[(size_t)h*S_+base+e]=0.f;
  }
}

// ---------------- v (b,s,n*DH+d) -> vT (h, d, s) ----------------
__global__ __launch_bounds__(256) void transpose_v(const bf16* __restrict__ v,
    bf16* __restrict__ vT){
  int sb = blockIdx.x, db = blockIdx.y, h = blockIdx.z;
  int b = h >> 2, n = h & 3;
  int s0 = sb*64, d0 = db*64;
  __shared__ short tl[64*LS];
  int tid = threadIdx.x;
  #pragma unroll
  for (int i=0;i<2;i++){
    int vv = tid + i*256; int r = vv>>3, c8 = vv&7;
    uint4 x = *(const uint4*)(v + (size_t)(b*S_+s0+r)*INNER_ + n*DH_ + d0 + c8*8);
    *(uint4*)&tl[r*LS + c8*8] = x;
  }
  __syncthreads();
  #pragma unroll
  for (int i=0;i<2;i++){
    int vv = tid + i*256; int r = vv>>3, c8 = vv&7;   // r = local d, c8 = s-chunk
    unsigned short tmp[8];
    #pragma unroll
    for (int e=0;e<8;e++) tmp[e] = (unsigned short)tl[(c8*8+e)*LS + r];
    uint4 o; __builtin_memcpy(&o, tmp, 16);
    *(uint4*)(vT + ((size_t)h*DH_ + d0 + r)*S_ + s0 + c8*8) = o;
  }
}

// ---------------- W = (Q K^T)*scale*exp(a_j - M_i), causal; + rowsums ----------------
// 128x128 i x j tiles, lower triangle; grid 8*136, h = bid&7 (XCD-pinned).
// Double-buffered d-tiles, stage-early + single __syncthreads per tile.
__global__ __launch_bounds__(256) void qk_decay_kernel(const bf16* __restrict__ qg,
    const bf16* __restrict__ kg, const float* __restrict__ ap,
    const float* __restrict__ Mp, float* __restrict__ rowsum, bf16* __restrict__ W){
  int h = blockIdx.x & 7;
  int t = 135 - (blockIdx.x >> 3);
  int p = (int)((sqrtf(8.f*t+1.f)-1.f)*0.5f);
  while ((p+1)*(p+2)/2 <= t) p++;
  while (p*(p+1)/2 > t) p--;
  int tj = t - p*(p+1)/2;
  int b = h >> 2, n = h & 3;
  int i0 = p*128, j0 = tj*128;
  __shared__ __align__(16) short smem[32768];  // 2 slots x (Qs 8192 | Ks 8192); reused for W repack
  __shared__ float a_s[128], m_s[128];
  int tid = threadIdx.x;
  if (tid < 128){
    a_s[tid] = ap[(size_t)h*S_ + j0 + tid];
    m_s[tid] = Mp[(size_t)h*S_ + i0 + tid];
  }
  int w = tid>>6, l = tid&63, lq = l>>4, lr = l&15;
  int wm = (w>>1)*64, wn = (w&1)*64;
  const bf16* Qbase = qg + (size_t)(b*S_+i0)*INNER_ + n*DH_;
  const bf16* Kbase = kg + (size_t)(b*S_+j0)*INNER_ + n*DH_;
  floatx4 acc[4][4];
  #pragma unroll
  for (int mi=0;mi<4;mi++){
    #pragma unroll
    for (int ni=0;ni<4;ni++) acc[mi][ni] = (floatx4){0.f,0.f,0.f,0.f};
  }
  short* Qs0 = smem;          short* Ks0 = smem + 8192;
  short* Qs1 = smem + 16384;  short* Ks1 = smem + 24576;
  // prologue: stage d-tile 0
  #pragma unroll
  for (int kk=0;kk<4;kk++){
    STAGE_ASYNC(Qs0, Qbase, INNER_, kk);
    STAGE_ASYNC(Ks0, Kbase, INNER_, kk);
  }
  __syncthreads();
  const int NT = DH_/64;   // 8
  for (int tt=0; tt<NT; ++tt){
    short* Qs  = (tt&1) ? Qs1 : Qs0;
    short* Ks  = (tt&1) ? Ks1 : Ks0;
    short* Qsn = (tt&1) ? Qs0 : Qs1;
    short* Ksn = (tt&1) ? Ks0 : Ks1;
    if (tt+1 < NT){
      int d0 = (tt+1)*64;
      #pragma unroll
      for (int kk=0;kk<4;kk++){
        STAGE_ASYNC(Qsn, Qbase + d0, INNER_, kk);
        STAGE_ASYNC(Ksn, Kbase + d0, INNER_, kk);
      }
    }
    #pragma unroll
    for (int ks=0; ks<2; ks++){
      bf16x8 af[4], bfr[4];
      #pragma unroll
      for (int mi=0;mi<4;mi++) af[mi] = *(const bf16x8*)&Qs[so_(wm+mi*16+lr, ks*4+lq)];
      #pragma unroll
      for (int ni=0;ni<4;ni++) bfr[ni] = *(const bf16x8*)&Ks[so_(wn+ni*16+lr, ks*4+lq)];
      #pragma unroll
      for (int mi=0;mi<4;mi++){
        #pragma unroll
        for (int ni=0;ni<4;ni++)
          acc[mi][ni] = __builtin_amdgcn_mfma_f32_16x16x32_bf16(af[mi], bfr[ni], acc[mi][ni], 0,0,0);
      }
    }
    __syncthreads();
  }
  const float scale = 0.04419417382415922f;   // 1/sqrt(512)
  float rpart[4][4];
  #pragma unroll
  for (int mi=0;mi<4;mi++){
    #pragma unroll
    for (int r=0;r<4;r++) rpart[mi][r]=0.f;
  }
  // loop-final __syncthreads separates compute reads from W repack writes
  #pragma unroll
  for (int mi=0;mi<4;mi++){
    #pragma unroll
    for (int ni=0;ni<4;ni++){
      int coll = wn + ni*16 + lr;
      int ch = coll>>3, off = coll&7;
      float av = a_s[coll];
      #pragma unroll
      for (int r=0;r<4;r++){
        int rowl = wm + mi*16 + lq*4 + r;
        int gi = i0 + rowl, gj = j0 + coll;
        float wv = 0.f;
        if (gj <= gi) wv = acc[mi][ni][r]*scale*__expf(av-m_s[rowl]);
        smem[rowl*128 + (((ch) ^ (rowl&15))<<3) + off] = (short)f2bu(wv);
        rpart[mi][r] += wv;
      }
    }
  }
  __syncthreads();
  #pragma unroll
  for (int i=0;i<8;i++){
    int slot = i*256 + tid;
    int r = slot >> 4, c8 = slot & 15;
    uint4 val = *(const uint4*)&smem[eo_(r, c8)];
    *(uint4*)(W + ((size_t)h*S_ + i0 + r)*S_ + j0 + c8*8) = val;
  }
  #pragma unroll
  for (int mi=0;mi<4;mi++){
    #pragma unroll
    for (int r=0;r<4;r++){
      float v = rpart[mi][r];
      v += __shfl_xor(v, 1, 16);
      v += __shfl_xor(v, 2, 16);
      v += __shfl_xor(v, 4, 16);
      v += __shfl_xor(v, 8, 16);
      if (lr == 0)
        atomicAdd(&rowsum[(size_t)h*S_ + i0 + wm + mi*16 + lq*4 + r], v);
    }
  }
}

// ---------------- O = (W * inv_row) @ V  (causal k-range), inv fused ----------------
// 128-row i-tiles x 128-d tiles: grid 8*64; h = bid&7 (XCD-pinned); ti descending.
// Double-buffered j-tiles, stage-early + single __syncthreads per tile.
__global__ __launch_bounds__(256) void pv_kernel(const bf16* __restrict__ W,
    const bf16* __restrict__ vT, const float* __restrict__ rowsum,
    const float* __restrict__ fl, bf16* __restrict__ O){
  int h = blockIdx.x & 7;
  int s = blockIdx.x >> 3;
  int ti = 15 - (s >> 2), tn = s & 3;
  int b = h >> 2, n = h & 3;
  int i0 = ti*128, d0 = tn*128;
  __shared__ __align__(16) short smem[32768];  // 2 slots x (Ws 8192 | Vs 8192); reused for O repack
  __shared__ float inv_s[128];
  int tid = threadIdx.x;
  if (tid < 128){
    size_t o = (size_t)h*S_ + i0 + tid;
    inv_s[tid] = 1.f/(fmaxf(fabsf(rowsum[o]), fl[o]) + EPS_CELL);
  }
  int w = tid>>6, l = tid&63, lq = l>>4, lr = l&15;
  int wm = (w>>1)*64, wn = (w&1)*64;
  const bf16* Wbase = W + ((size_t)h*S_ + i0)*S_;
  const bf16* Vbase = vT + ((size_t)h*DH_ + d0)*S_;
  floatx4 acc[4][4];
  #pragma unroll
  for (int mi=0;mi<4;mi++){
    #pragma unroll
    for (int ni=0;ni<4;ni++) acc[mi][ni] = (floatx4){0.f,0.f,0.f,0.f};
  }
  short* Ws0 = smem;          short* Vs0 = smem + 8192;
  short* Ws1 = smem + 16384;  short* Vs1 = smem + 24576;
  int NT = (i0 >> 6) + 2;    // causal j-tiles of 64 covering j <= i0+127
  // prologue: stage j-tile 0
  #pragma unroll
  for (int kk=0;kk<4;kk++){
    STAGE_ASYNC(Ws0, Wbase, S_, kk);
    STAGE_ASYNC(Vs0, Vbase, S_, kk);
  }
  __syncthreads();
  for (int tt=0; tt<NT; ++tt){
    short* Ws  = (tt&1) ? Ws1 : Ws0;
    short* Vs  = (tt&1) ? Vs1 : Vs0;
    short* Wsn = (tt&1) ? Ws0 : Ws1;
    short* Vsn = (tt&1) ? Vs0 : Vs1;
    if (tt+1 < NT){
      int j0 = (tt+1)*64;
      #pragma unroll
      for (int kk=0;kk<4;kk++){
        STAGE_ASYNC(Wsn, Wbase + j0, S_, kk);
        STAGE_ASYNC(Vsn, Vbase + j0, S_, kk);
      }
    }
    #pragma unroll
    for (int ks=0; ks<2; ks++){
      bf16x8 af[4], bfr[4];
      #pragma unroll
      for (int mi=0;mi<4;mi++) af[mi] = *(const bf16x8*)&Ws[so_(wm+mi*16+lr, ks*4+lq)];
      #pragma unroll
      for (int ni=0;ni<4;ni++) bfr[ni] = *(const bf16x8*)&Vs[so_(wn+ni*16+lr, ks*4+lq)];
      #pragma unroll
      for (int mi=0;mi<4;mi++){
        #pragma unroll
        for (int ni=0;ni<4;ni++)
          acc[mi][ni] = __builtin_amdgcn_mfma_f32_16x16x32_bf16(af[mi], bfr[ni], acc[mi][ni], 0,0,0);
      }
    }
    __syncthreads();
  }
  // loop-final __syncthreads separates compute reads from O repack writes
  #pragma unroll
  for (int mi=0;mi<4;mi++){
    #pragma unroll
    for (int ni=0;ni<4;ni++){
      int dl = wn + ni*16 + lr;
      int ch = dl>>3, off = dl&7;
      #pragma unroll
      for (int r=0;r<4;r++){
        int rowl = wm + mi*16 + lq*4 + r;
        smem[rowl*128 + (((ch) ^ (rowl&15))<<3) + off] = (short)f2bu(acc[mi][ni][r] * inv_s[rowl]);
      }
    }
  }
  __syncthreads();
  #pragma unroll
  for (int i=0;i<8;i++){
    int slot = i*256 + tid;
    int r = slot >> 4, c8 = slot & 15;
    uint4 val = *(const uint4*)&smem[eo_(r, c8)];
    *(uint4*)(O + (size_t)(b*S_ + i0 + r)*INNER_ + n*DH_ + d0 + c8*8) = val;
  }
}

// ---------------- head groupnorm + skip + output gate (in-place into z) ----------
__global__ __launch_bounds__(256) void headnorm_gate(const bf16* __restrict__ h,
    const float* __restrict__ onw, const float* __restrict__ skip,
    const bf16* __restrict__ xca, bf16* __restrict__ up){
  int bid = blockIdx.x;
  int n = bid & 3; int bs = bid >> 2;
  int tid = threadIdx.x;
  size_t hbase = (size_t)bs*INNER_ + n*DH_;
  float v0 = b2f(h[hbase+tid]);
  float v1 = b2f(h[hbase+256+tid]);
  __shared__ float sa[256], sb[256];
  sa[tid]=v0+v1; sb[tid]=v0*v0+v1*v1;
  __syncthreads();
  for (int off=128; off>0; off>>=1){
    if (tid<off){ sa[tid]+=sa[tid+off]; sb[tid]+=sb[tid+off]; }
    __syncthreads();
  }
  float mean = sa[0]*(1.f/DH_);
  float var  = sb[0]*(1.f/DH_) - mean*mean;
  float rstd = rsqrtf(var + LN_EPS_);
  #pragma unroll
  for (int e=0;e<2;e++){
    int dl = e*256+tid; int c = n*DH_+dl;
    float hv = e ? v1 : v0;
    float hn = (hv-mean)*rstd*onw[c];
    float hs = hn + skip[c]*b2f(xca[(size_t)bs*INNER_+c]);
    size_t zoff = (size_t)bs*(2*INNER_) + INNER_ + c;
    float zv = b2f(up[zoff]);
    float sz = zv/(1.f+expf(-zv));
    up[zoff] = f2b(hs*sz);
  }
}

extern "C" void kernel_launch(void* const* d_in, const int* in_sizes, int n_in,
                              void* d_out, int out_size, void* d_ws, size_t ws_size,
                              hipStream_t stream) {
  const float* x      = (const float*)d_in[0];
  const float* w_in   = (const float*)d_in[1];
  const float* b_in   = (const float*)d_in[2];
  const float* ln1_w  = (const float*)d_in[3];
  const float* w_up   = (const float*)d_in[4];
  const float* b_up   = (const float*)d_in[5];
  const float* conv_w = (const float*)d_in[6];
  const float* conv_b = (const float*)d_in[7];
  const float* q_w    = (const float*)d_in[8];
  const float* q_b    = (const float*)d_in[9];
  const float* k_w    = (const float*)d_in[10];
  const float* k_b    = (const float*)d_in[11];
  const float* v_w    = (const float*)d_in[12];
  const float* v_b    = (const float*)d_in[13];
  const float* ig_w   = (const float*)d_in[14];
  const float* ig_b   = (const float*)d_in[15];
  const float* fg_w   = (const float*)d_in[16];
  const float* fg_b   = (const float*)d_in[17];
  const float* onw    = (const float*)d_in[18];
  const float* skip   = (const float*)d_in[19];
  const float* w_down = (const float*)d_in[20];
  const float* b_down = (const float*)d_in[21];
  const float* post_w = (const float*)d_in[22];

  char* p = (char*)d_ws;
  auto alloc = [&](size_t bytes)->void*{ void* r = p; p += (bytes + 255) & ~(size_t)255; return r; };
  bf16* h_in = (bf16*)alloc((size_t)T_*E_*2);        // 8 MB
  bf16* xn   = (bf16*)alloc((size_t)T_*E_*2);        // 8 MB (reused as y later)
  bf16* up   = (bf16*)alloc((size_t)T_*2*INNER_*2);  // 32 MB (x_m | z; z later holds h_gated)
  bf16* xca  = (bf16*)alloc((size_t)T_*INNER_*2);    // 16 MB
  bf16* qb_  = (bf16*)alloc((size_t)T_*INNER_*2);
  bf16* kb_  = (bf16*)alloc((size_t)T_*INNER_*2);
  bf16* vb_  = (bf16*)alloc((size_t)T_*INNER_*2);    // v; later reused as attention O
  bf16* hb_  = (bf16*)alloc((size_t)T_*INNER_*2);    // reused as vT (h,d,s)
  float* igbuf = (float*)alloc((size_t)B_*NH_*S_*4);
  float* fgbuf = (float*)alloc((size_t)B_*NH_*S_*4);
  float* abuf  = (float*)alloc((size_t)B_*NH_*S_*4);
  float* Mbuf  = (float*)alloc((size_t)B_*NH_*S_*4);
  float* flbuf = (float*)alloc((size_t)B_*NH_*S_*4);
  float* rsbuf = (float*)alloc((size_t)B_*NH_*S_*4);
  bf16* gwb  = (bf16*)alloc((size_t)3*INNER_*8*2);   // 96 KB packed gate weights
  bf16* Wbuf = (bf16*)alloc((size_t)B_*NH_*S_*S_*2); // 67 MB decay-weighted scores
  bf16* ybuf = xn;   // xn dead after up-projection
  bf16* vTb  = hb_;
  bf16* obuf = vb_;
  // converted-weight scratch overlapping Wbuf (dead until qk_decay / after pv)
  bf16* xbf    = Wbuf;                               // 4 MB, dead after GEMM1
  bf16* w_in_t = Wbuf + (size_t)T_*IN_;              // 1 MB, dead after GEMM1
  bf16* w_up_t = w_in_t + (size_t)E_*IN_;            // 8 MB, dead after GEMM2
  bf16* w_down_t = Wbuf;                             // written AFTER pv_kernel frees Wbuf

  // 0a. convert x -> bf16 ; transpose+convert w_in, w_up ; pack gate weights
  convert_bf16<<<(T_*IN_/8+255)/256, 256, 0, stream>>>(x, xbf, T_*IN_/8);
  transpose_conv_w<<<dim3(E_/64, IN_/64), 256, 0, stream>>>(w_in, w_in_t, IN_, E_);
  transpose_conv_w<<<dim3((2*INNER_)/64, E_/64), 256, 0, stream>>>(w_up, w_up_t, E_, 2*INNER_);
  pack_gates_w<<<(3*INNER_+255)/256, 256, 0, stream>>>(ig_w, fg_w, gwb);
  // 1. h_in = x @ w_in + b_in     (MM=32, NN=8)
  mfma_gemm<<<(T_/128)*(E_/128), 256, 0, stream>>>(xbf, w_in_t, b_in, h_in, IN_, IN_, E_, E_/128);
  // 2. xn = LN(h_in)*ln1_w
  ln_rows<bf16><<<T_, 256, 0, stream>>>(h_in, nullptr, ln1_w, xn);
  // 3. up = xn @ w_up + b_up   (x_m | z)  (MM=32, NN=32)
  mfma_gemm<<<(T_/128)*((2*INNER_)/128), 256, 0, stream>>>(xn, w_up_t, b_up, up, E_, E_, 2*INNER_, (2*INNER_)/128);
  // 4+5. fused conv+SiLU and q/k/v projections (4 tokens/block, all-vector)
  conv_headwise<<<T_/CTB_, 256, 0, stream>>>(up, conv_w, conv_b,
      q_w, q_b, k_w, k_b, v_w, v_b, xca, qb_, kb_, vb_);
  // 6. gate pre-activations (register-resident GEMV, 8 tokens/block)
  gates_kernel<<<T_/8, 256, 0, stream>>>(qb_, kb_, vb_, gwb, ig_b, fg_b, igbuf, fgbuf);
  // 7. scans: a, M, floor; zero rowsums
  scan8<<<B_*NH_, 256, 0, stream>>>(igbuf, fgbuf, abuf, Mbuf, flbuf, rsbuf);
  // 8. v -> vT (head-major, d-major)
  transpose_v<<<dim3(S_/64, DH_/64, B_*NH_), 256, 0, stream>>>(vb_, vTb);
  // 9. W = QK^T * scale * decay (128x128 lower-triangle tiles, head XCD-pinned), rowsums
  qk_decay_kernel<<<8*136, 256, 0, stream>>>(qb_, kb_, abuf, Mbuf, rsbuf, Wbuf);
  // 10. O = (W*inv) @ V -> obuf; inv fused, head XCD-pinned, 128-row tiles
  pv_kernel<<<8*64, 256, 0, stream>>>(Wbuf, vTb, rsbuf, flbuf, obuf);
  // 11. headnorm + skip + output gate, written in place over z
  headnorm_gate<<<T_*NH_, 256, 0, stream>>>(obuf, onw, skip, xca, up);
  // 11b. transpose+convert w_down (Wbuf now dead)
  transpose_conv_w<<<dim3(E_/64, INNER_/64), 256, 0, stream>>>(w_down, w_down_t, INNER_, E_);
  // 12. y = h_gated @ w_down + b_down  (MM=32, NN=8)
  mfma_gemm<<<(T_/128)*(E_/128), 256, 0, stream>>>(up + INNER_, w_down_t, b_down, ybuf, INNER_, 2*INNER_, E_, E_/128);
  // 13. out = LN(h_in + y)*post_w
  ln_rows<float><<<T_, 256, 0, stream>>>(h_in, ybuf, post_w, (float*)d_out);
}

// Round 6
// 373.319 us; speedup vs baseline: 1.0766x; 1.0766x over previous
//
#include <hip/hip_runtime.h>
#include <hip/hip_bf16.h>

typedef __hip_bfloat16 bf16;
typedef float floatx4 __attribute__((ext_vector_type(4)));
typedef short bf16x8 __attribute__((ext_vector_type(8)));

#define B_      2
#define S_      2048
#define IN_     512
#define E_      1024
#define INNER_  2048
#define NH_     4
#define DH_     512
#define T_      (B_*S_)      // 4096 tokens
#define EPS_CELL 1e-6f
#define LN_EPS_  1e-5f
#define LS      72           // padded LDS row stride (shorts) for non-async kernels
#define CTB_    4            // tokens per block in conv_headwise

__device__ inline float b2f(bf16 x){ return __bfloat162float(x); }
__device__ inline bf16  f2b(float x){ return __float2bfloat16(x); }
__device__ inline float u2f(unsigned int u){ union{unsigned int i; float f;} v; v.i = u; return v.f; }
__device__ inline unsigned short f2bu(float x){ bf16 t = __float2bfloat16(x); unsigned short r; __builtin_memcpy(&r,&t,2); return r; }
__device__ inline void unpack8(uint4 u, float* f){
  f[0]=u2f(u.x<<16); f[1]=u2f(u.x&0xffff0000u);
  f[2]=u2f(u.y<<16); f[3]=u2f(u.y&0xffff0000u);
  f[4]=u2f(u.z<<16); f[5]=u2f(u.z&0xffff0000u);
  f[6]=u2f(u.w<<16); f[7]=u2f(u.w&0xffff0000u);
}
__device__ inline uint4 pack8(const float* f){
  uint4 u;
  u.x = (unsigned)f2bu(f[0]) | ((unsigned)f2bu(f[1])<<16);
  u.y = (unsigned)f2bu(f[2]) | ((unsigned)f2bu(f[3])<<16);
  u.z = (unsigned)f2bu(f[4]) | ((unsigned)f2bu(f[5])<<16);
  u.w = (unsigned)f2bu(f[6]) | ((unsigned)f2bu(f[7])<<16);
  return u;
}
__device__ inline void stv(bf16* p, float v){ *p = f2b(v); }
__device__ inline void stv(float* p, float v){ *p = v; }

// ---- async 16B global->LDS copy (wave-uniform base + lane*16 pattern) ----
typedef __attribute__((address_space(3))) unsigned int lds_u32_t;
typedef __attribute__((address_space(1))) const unsigned int glb_u32_t;
__device__ __forceinline__ void cp_async16(const bf16* g, short* l){
  __builtin_amdgcn_global_load_lds((glb_u32_t*)(const void*)g,
                                   (lds_u32_t*)(void*)l, 16, 0, 0);
}
// swizzled LDS offset (shorts) for Nx64 tile: row-dense, chunk XOR row&7
__device__ __forceinline__ int so_(int row, int c8){ return row*64 + (((c8) ^ (row&7))<<3); }
// epilogue repack offset for Nx128-short tile: chunk XOR row&15
__device__ __forceinline__ int eo_(int row, int ch){ return row*128 + (((ch) ^ (row&15))<<3); }

// stage rows of a {64,128}x64-short tile (row stride `stride` in global)
#define STAGE_ASYNC(dst, srcbase, stride, kk) \
  { int slot_ = (kk)*256 + tid; int r_ = slot_>>3; int c8_ = (slot_&7) ^ (r_&7); \
    cp_async16((srcbase) + (size_t)r_*(stride) + c8_*8, &dst[slot_*8]); }

// ---------------- W[K,N] fp32 -> Wt[N,K] bf16 (64x64 LDS tile), device body ----
__device__ inline void transpose_tile(const float* W, bf16* Wt, int K, int N,
    int n0, int k0, int tid, float (*tl)[65]){
  #pragma unroll
  for (int i=0;i<4;i++){
    int idx = tid + i*256; int r = idx>>4, c4 = idx&15;
    float4 v = *(const float4*)(W + (size_t)(k0+r)*N + n0 + c4*4);
    tl[r][c4*4+0]=v.x; tl[r][c4*4+1]=v.y; tl[r][c4*4+2]=v.z; tl[r][c4*4+3]=v.w;
  }
  __syncthreads();
  #pragma unroll
  for (int i=0;i<4;i++){
    int idx = tid + i*256; int rn = idx>>4, c4 = idx&15;
    ushort4 o;
    o.x=f2bu(tl[c4*4+0][rn]); o.y=f2bu(tl[c4*4+1][rn]);
    o.z=f2bu(tl[c4*4+2][rn]); o.w=f2bu(tl[c4*4+3][rn]);
    *(ushort4*)(Wt + (size_t)(n0+rn)*K + k0 + c4*4) = o;
  }
}

// ---------------- fused prep: convert x | transpose w_in | transpose w_up | pack gates ----
// grid = 1024 (convert) + 128 (w_in) + 1024 (w_up) + 24 (pack) = 2200
__global__ __launch_bounds__(256) void prep_fused(const float* __restrict__ x,
    const float* __restrict__ w_in, const float* __restrict__ w_up,
    const float* __restrict__ igw, const float* __restrict__ fgw,
    bf16* __restrict__ xbf, bf16* __restrict__ w_in_t, bf16* __restrict__ w_up_t,
    bf16* __restrict__ gwb){
  __shared__ float tl[64][65];
  int bid = blockIdx.x, tid = threadIdx.x;
  if (bid < 1024){
    // convert x -> bf16, 8 floats/thread
    int i = bid*256 + tid;
    const float4* p = (const float4*)(x) + i*2;
    float4 a = p[0], b = p[1];
    ushort4 o0, o1;
    o0.x=f2bu(a.x); o0.y=f2bu(a.y); o0.z=f2bu(a.z); o0.w=f2bu(a.w);
    o1.x=f2bu(b.x); o1.y=f2bu(b.y); o1.z=f2bu(b.z); o1.w=f2bu(b.w);
    ushort4* q = (ushort4*)(xbf) + i*2;
    q[0]=o0; q[1]=o1;
  } else if (bid < 1152){
    int id = bid - 1024;               // 16 n-blocks x 8 k-blocks
    int n0 = (id & 15)*64, k0 = (id >> 4)*64;
    transpose_tile(w_in, w_in_t, IN_, E_, n0, k0, tid, tl);
  } else if (bid < 2176){
    int id = bid - 1152;               // 64 n-blocks x 16 k-blocks
    int n0 = (id & 63)*64, k0 = (id >> 6)*64;
    transpose_tile(w_up, w_up_t, E_, 2*INNER_, n0, k0, tid, tl);
  } else {
    int idx = (bid - 2176)*256 + tid;
    if (idx < 3*INNER_){
      int g = idx >> 9;
      int e = (idx >> 6) & 7;
      int l = idx & 63;
      int r = g*512 + l*8 + e;
      float4 a = *(const float4*)(igw + (size_t)r*4);
      float4 b = *(const float4*)(fgw + (size_t)r*4);
      ushort4 o0, o1;
      o0.x=f2bu(a.x); o0.y=f2bu(a.y); o0.z=f2bu(a.z); o0.w=f2bu(a.w);
      o1.x=f2bu(b.x); o1.y=f2bu(b.y); o1.z=f2bu(b.z); o1.w=f2bu(b.w);
      *(ushort4*)(gwb + (size_t)idx*8)     = o0;
      *(ushort4*)(gwb + (size_t)idx*8 + 4) = o1;
    }
  }
}

// ---------------- MFMA GEMM 128x128: C = A @ Bt^T + bias ----------------
// 2-phase double-buffered LDS; stage t+1 issued before compute t; one barrier/tile.
__global__ __launch_bounds__(256) void mfma_gemm(const bf16* __restrict__ A,
    const bf16* __restrict__ Bt, const float* __restrict__ bias, bf16* __restrict__ C,
    int Kd, int lda, int ldc, int NN){
  int bid = blockIdx.x;
  int MM = gridDim.x / NN;
  int mPerX = MM >> 3;
  int xcd = bid & 7, seq = bid >> 3;
  int nb = seq % NN, mb = xcd*mPerX + seq / NN;
  int n0 = nb*128, m0 = mb*128;
  __shared__ __align__(16) short smem[32768];
  int tid = threadIdx.x;
  int w = tid>>6, l = tid&63, lq = l>>4, lr = l&15;
  int wm = (w>>1)*64, wn = (w&1)*64;
  const bf16* Abase = A + (size_t)m0*lda;
  const bf16* Bbase = Bt + (size_t)n0*Kd;
  floatx4 acc[4][4];
  #pragma unroll
  for (int mi=0;mi<4;mi++){
    #pragma unroll
    for (int ni=0;ni<4;ni++) acc[mi][ni] = (floatx4){0.f,0.f,0.f,0.f};
  }
  short* As0 = smem;          short* Bs0 = smem + 8192;
  short* As1 = smem + 16384;  short* Bs1 = smem + 24576;
  int NT = Kd >> 6;
  #pragma unroll
  for (int kk=0;kk<4;kk++){
    STAGE_ASYNC(As0, Abase, lda, kk);
    STAGE_ASYNC(Bs0, Bbase, Kd, kk);
  }
  __syncthreads();
  for (int t=0; t<NT; ++t){
    short* As  = (t&1) ? As1 : As0;
    short* Bs  = (t&1) ? Bs1 : Bs0;
    short* Asn = (t&1) ? As0 : As1;
    short* Bsn = (t&1) ? Bs0 : Bs1;
    if (t+1 < NT){
      int k0 = (t+1)*64;
      #pragma unroll
      for (int kk=0;kk<4;kk++){
        STAGE_ASYNC(Asn, Abase + k0, lda, kk);
        STAGE_ASYNC(Bsn, Bbase + k0, Kd, kk);
      }
    }
    #pragma unroll
    for (int ks=0; ks<2; ks++){
      bf16x8 af[4], bfr[4];
      #pragma unroll
      for (int mi=0;mi<4;mi++) af[mi] = *(const bf16x8*)&As[so_(wm+mi*16+lr, ks*4+lq)];
      #pragma unroll
      for (int ni=0;ni<4;ni++) bfr[ni] = *(const bf16x8*)&Bs[so_(wn+ni*16+lr, ks*4+lq)];
      #pragma unroll
      for (int mi=0;mi<4;mi++){
        #pragma unroll
        for (int ni=0;ni<4;ni++)
          acc[mi][ni] = __builtin_amdgcn_mfma_f32_16x16x32_bf16(af[mi], bfr[ni], acc[mi][ni], 0,0,0);
      }
    }
    __syncthreads();
  }
  float bb[4];
  #pragma unroll
  for (int ni=0;ni<4;ni++) bb[ni] = bias[n0 + wn + ni*16 + lr];
  #pragma unroll
  for (int mi=0;mi<4;mi++){
    #pragma unroll
    for (int ni=0;ni<4;ni++){
      int coll = wn + ni*16 + lr;
      int ch = coll>>3, off = coll&7;
      #pragma unroll
      for (int r=0;r<4;r++){
        int rowl = wm + mi*16 + lq*4 + r;
        smem[rowl*128 + (((ch) ^ (rowl&15))<<3) + off] = (short)f2bu(acc[mi][ni][r] + bb[ni]);
      }
    }
  }
  __syncthreads();
  #pragma unroll
  for (int i=0;i<8;i++){
    int slot = i*256 + tid;
    int r = slot >> 4, c8 = slot & 15;
    uint4 val = *(const uint4*)&smem[eo_(r, c8)];
    *(uint4*)(C + (size_t)(m0+r)*ldc + n0 + c8*8) = val;
  }
}

// ---------------- MFMA GEMM 64x128 tile (for N=1024 GEMMs: 512 blocks = 2/CU) ----
__global__ __launch_bounds__(256) void mfma_gemm64(const bf16* __restrict__ A,
    const bf16* __restrict__ Bt, const float* __restrict__ bias, bf16* __restrict__ C,
    int Kd, int lda, int ldc, int NN){
  int bid = blockIdx.x;
  int MM = gridDim.x / NN;          // m-tiles of 64
  int mPerX = MM >> 3;
  int xcd = bid & 7, seq = bid >> 3;
  int nb = seq % NN, mb = xcd*mPerX + seq / NN;
  int n0 = nb*128, m0 = mb*64;
  __shared__ __align__(16) short smem[24576];   // 2 x (A 4096 | B 8192); reused for C repack
  int tid = threadIdx.x;
  int w = tid>>6, l = tid&63, lq = l>>4, lr = l&15;
  int wm = (w>>1)*32, wn = (w&1)*64;
  const bf16* Abase = A + (size_t)m0*lda;
  const bf16* Bbase = Bt + (size_t)n0*Kd;
  floatx4 acc[2][4];
  #pragma unroll
  for (int mi=0;mi<2;mi++){
    #pragma unroll
    for (int ni=0;ni<4;ni++) acc[mi][ni] = (floatx4){0.f,0.f,0.f,0.f};
  }
  short* As0 = smem;          short* Bs0 = smem + 4096;
  short* As1 = smem + 12288;  short* Bs1 = smem + 16384;
  int NT = Kd >> 6;
  STAGE_ASYNC(As0, Abase, lda, 0);
  STAGE_ASYNC(As0, Abase, lda, 1);
  #pragma unroll
  for (int kk=0;kk<4;kk++){ STAGE_ASYNC(Bs0, Bbase, Kd, kk); }
  __syncthreads();
  for (int t=0; t<NT; ++t){
    short* As  = (t&1) ? As1 : As0;
    short* Bs  = (t&1) ? Bs1 : Bs0;
    short* Asn = (t&1) ? As0 : As1;
    short* Bsn = (t&1) ? Bs0 : Bs1;
    if (t+1 < NT){
      int k0 = (t+1)*64;
      STAGE_ASYNC(Asn, Abase + k0, lda, 0);
      STAGE_ASYNC(Asn, Abase + k0, lda, 1);
      #pragma unroll
      for (int kk=0;kk<4;kk++){ STAGE_ASYNC(Bsn, Bbase + k0, Kd, kk); }
    }
    #pragma unroll
    for (int ks=0; ks<2; ks++){
      bf16x8 af[2], bfr[4];
      #pragma unroll
      for (int mi=0;mi<2;mi++) af[mi] = *(const bf16x8*)&As[so_(wm+mi*16+lr, ks*4+lq)];
      #pragma unroll
      for (int ni=0;ni<4;ni++) bfr[ni] = *(const bf16x8*)&Bs[so_(wn+ni*16+lr, ks*4+lq)];
      #pragma unroll
      for (int mi=0;mi<2;mi++){
        #pragma unroll
        for (int ni=0;ni<4;ni++)
          acc[mi][ni] = __builtin_amdgcn_mfma_f32_16x16x32_bf16(af[mi], bfr[ni], acc[mi][ni], 0,0,0);
      }
    }
    __syncthreads();
  }
  float bb[4];
  #pragma unroll
  for (int ni=0;ni<4;ni++) bb[ni] = bias[n0 + wn + ni*16 + lr];
  #pragma unroll
  for (int mi=0;mi<2;mi++){
    #pragma unroll
    for (int ni=0;ni<4;ni++){
      int coll = wn + ni*16 + lr;
      int ch = coll>>3, off = coll&7;
      #pragma unroll
      for (int r=0;r<4;r++){
        int rowl = wm + mi*16 + lq*4 + r;
        smem[rowl*128 + (((ch) ^ (rowl&15))<<3) + off] = (short)f2bu(acc[mi][ni][r] + bb[ni]);
      }
    }
  }
  __syncthreads();
  #pragma unroll
  for (int i=0;i<4;i++){
    int slot = i*256 + tid;
    int r = slot >> 4, c8 = slot & 15;
    uint4 val = *(const uint4*)&smem[eo_(r, c8)];
    *(uint4*)(C + (size_t)(m0+r)*ldc + n0 + c8*8) = val;
  }
}

// ---------------- layernorm over rows of length E_ (opt. fused add) ----------------
template<typename OutT>
__global__ __launch_bounds__(256) void ln_rows(const bf16* __restrict__ X,
    const bf16* __restrict__ Xadd, const float* __restrict__ w, OutT* __restrict__ Y){
  int row = blockIdx.x, tid = threadIdx.x;
  size_t base = (size_t)row*E_;
  float vals[4], s=0.f, s2=0.f;
  #pragma unroll
  for (int e=0;e<4;e++){
    int c = e*256+tid;
    float v = b2f(X[base+c]);
    if (Xadd) v += b2f(Xadd[base+c]);
    vals[e]=v; s+=v; s2+=v*v;
  }
  __shared__ float sa[256], sb[256];
  sa[tid]=s; sb[tid]=s2; __syncthreads();
  for (int off=128; off>0; off>>=1){
    if (tid<off){ sa[tid]+=sa[tid+off]; sb[tid]+=sb[tid+off]; }
    __syncthreads();
  }
  float mean = sa[0]*(1.f/E_);
  float var  = sb[0]*(1.f/E_) - mean*mean;
  float rstd = rsqrtf(var + LN_EPS_);
  #pragma unroll
  for (int e=0;e<4;e++){
    int c = e*256+tid;
    stv(&Y[base+c], (vals[e]-mean)*rstd*w[c]);
  }
}

// ---------------- fused causal conv(K=4)+SiLU and block-diagonal q/k/v ----------------
__global__ __launch_bounds__(256) void conv_headwise(const bf16* __restrict__ up,
    const float* __restrict__ cw, const float* __restrict__ cb,
    const float* __restrict__ qw, const float* __restrict__ qb,
    const float* __restrict__ kw, const float* __restrict__ kb,
    const float* __restrict__ vw, const float* __restrict__ vb,
    bf16* __restrict__ xca, bf16* __restrict__ q, bf16* __restrict__ k,
    bf16* __restrict__ v){
  int t0 = blockIdx.x*CTB_;
  int s0 = t0 & (S_-1);
  int c0 = threadIdx.x*8;
  int hw0 = c0 >> 2;

  float row[7][8];
  #pragma unroll
  for (int j=0;j<7;j++){
    if (s0-3+j >= 0){
      uint4 rv = *(const uint4*)(up + (size_t)(t0-3+j)*(2*INNER_) + c0);
      unpack8(rv, row[j]);
    } else {
      #pragma unroll
      for (int e=0;e<8;e++) row[j][e]=0.f;
    }
  }

  float xc[CTB_][8];
  {
    float cwv[8][4], cbv[8];
    #pragma unroll
    for (int e=0;e<8;e++){
      float4 w4 = *(const float4*)(cw + (size_t)(c0+e)*4);
      cwv[e][0]=w4.x; cwv[e][1]=w4.y; cwv[e][2]=w4.z; cwv[e][3]=w4.w;
    }
    float4 b0 = *(const float4*)(cb+c0), b1 = *(const float4*)(cb+c0+4);
    cbv[0]=b0.x; cbv[1]=b0.y; cbv[2]=b0.z; cbv[3]=b0.w;
    cbv[4]=b1.x; cbv[5]=b1.y; cbv[6]=b1.z; cbv[7]=b1.w;
    #pragma unroll
    for (int i=0;i<CTB_;i++){
      #pragma unroll
      for (int e=0;e<8;e++){
        float a = cbv[e];
        #pragma unroll
        for (int t=0;t<4;t++) a += row[i+t][e]*cwv[e][t];
        xc[i][e] = a/(1.f+expf(-a));
      }
      *(uint4*)(xca + (size_t)(t0+i)*INNER_ + c0) = pack8(xc[i]);
    }
  }

  {
    float wv_[32], bv[8];
    #pragma unroll
    for (int g=0;g<2;g++){
      #pragma unroll
      for (int r4=0;r4<4;r4++){
        float4 w4 = *(const float4*)(vw + (size_t)(hw0+g)*16 + r4*4);
        wv_[g*16+r4*4+0]=w4.x; wv_[g*16+r4*4+1]=w4.y;
        wv_[g*16+r4*4+2]=w4.z; wv_[g*16+r4*4+3]=w4.w;
      }
    }
    float4 b0 = *(const float4*)(vb+c0), b1 = *(const float4*)(vb+c0+4);
    bv[0]=b0.x; bv[1]=b0.y; bv[2]=b0.z; bv[3]=b0.w;
    bv[4]=b1.x; bv[5]=b1.y; bv[6]=b1.z; bv[7]=b1.w;
    #pragma unroll
    for (int i=0;i<CTB_;i++){
      float ov[8];
      #pragma unroll
      for (int g=0;g<2;g++){
        #pragma unroll
        for (int o=0;o<4;o++){
          float a = bv[g*4+o];
          #pragma unroll
          for (int d=0;d<4;d++) a += row[i+3][g*4+d]*wv_[g*16+o*4+d];
          ov[g*4+o]=a;
        }
      }
      *(uint4*)(v + (size_t)(t0+i)*INNER_ + c0) = pack8(ov);
    }
  }

  {
    float wv_[32], bv[8];
    #pragma unroll
    for (int g=0;g<2;g++){
      #pragma unroll
      for (int r4=0;r4<4;r4++){
        float4 w4 = *(const float4*)(qw + (size_t)(hw0+g)*16 + r4*4);
        wv_[g*16+r4*4+0]=w4.x; wv_[g*16+r4*4+1]=w4.y;
        wv_[g*16+r4*4+2]=w4.z; wv_[g*16+r4*4+3]=w4.w;
      }
    }
    float4 b0 = *(const float4*)(qb+c0), b1 = *(const float4*)(qb+c0+4);
    bv[0]=b0.x; bv[1]=b0.y; bv[2]=b0.z; bv[3]=b0.w;
    bv[4]=b1.x; bv[5]=b1.y; bv[6]=b1.z; bv[7]=b1.w;
    #pragma unroll
    for (int i=0;i<CTB_;i++){
      float ov[8];
      #pragma unroll
      for (int g=0;g<2;g++){
        #pragma unroll
        for (int o=0;o<4;o++){
          float a = bv[g*4+o];
          #pragma unroll
          for (int d=0;d<4;d++) a += xc[i][g*4+d]*wv_[g*16+o*4+d];
          ov[g*4+o]=a;
        }
      }
      *(uint4*)(q + (size_t)(t0+i)*INNER_ + c0) = pack8(ov);
    }
  }

  {
    float wv_[32], bv[8];
    #pragma unroll
    for (int g=0;g<2;g++){
      #pragma unroll
      for (int r4=0;r4<4;r4++){
        float4 w4 = *(const float4*)(kw + (size_t)(hw0+g)*16 + r4*4);
        wv_[g*16+r4*4+0]=w4.x; wv_[g*16+r4*4+1]=w4.y;
        wv_[g*16+r4*4+2]=w4.z; wv_[g*16+r4*4+3]=w4.w;
      }
    }
    float4 b0 = *(const float4*)(kb+c0), b1 = *(const float4*)(kb+c0+4);
    bv[0]=b0.x; bv[1]=b0.y; bv[2]=b0.z; bv[3]=b0.w;
    bv[4]=b1.x; bv[5]=b1.y; bv[6]=b1.z; bv[7]=b1.w;
    #pragma unroll
    for (int i=0;i<CTB_;i++){
      float ov[8];
      #pragma unroll
      for (int g=0;g<2;g++){
        #pragma unroll
        for (int o=0;o<4;o++){
          float a = bv[g*4+o];
          #pragma unroll
          for (int d=0;d<4;d++) a += xc[i][g*4+d]*wv_[g*16+o*4+d];
          ov[g*4+o]=a;
        }
      }
      *(uint4*)(k + (size_t)(t0+i)*INNER_ + c0) = pack8(ov);
    }
  }
}

// ---------------- fused: gates GEMV (512 blocks) | v->vT transpose (2048 blocks) ----
__global__ __launch_bounds__(256) void gates_transv(const bf16* __restrict__ q,
    const bf16* __restrict__ k, const bf16* __restrict__ v,
    const bf16* __restrict__ gwb, const float* __restrict__ igb,
    const float* __restrict__ fgb, float* __restrict__ igo, float* __restrict__ fgo,
    bf16* __restrict__ vT){
  __shared__ float red[4*32];
  __shared__ short tl[64*LS];
  int bid = blockIdx.x, tid = threadIdx.x;
  if (bid < 512){
    int w = tid >> 6, l = tid & 63;
    int quad = w >> 1, kh = w & 1;
    int tok0 = bid*8 + quad*4;
    float acc[4][8];
    #pragma unroll
    for (int t=0;t<4;t++){
      #pragma unroll
      for (int n=0;n<8;n++) acc[t][n]=0.f;
    }
    #pragma unroll 2
    for (int it=0; it<6; ++it){
      int src = it >> 1, j = it & 1;
      const bf16* sp = (src==0) ? q : ((src==1) ? k : v);
      int pos = kh*1024 + j*512 + l*8;
      int g = src*4 + kh*2 + j;
      uint4 dv[4];
      #pragma unroll
      for (int t=0;t<4;t++)
        dv[t] = *(const uint4*)(sp + (size_t)(tok0+t)*INNER_ + pos);
      float d[4][8];
      #pragma unroll
      for (int t=0;t<4;t++) unpack8(dv[t], d[t]);
      const bf16* wb = gwb + (size_t)g*512*8;
      #pragma unroll
      for (int e=0;e<8;e++){
        uint4 wv = *(const uint4*)(wb + (size_t)(e*64 + l)*8);
        float w8[8]; unpack8(wv, w8);
        #pragma unroll
        for (int t=0;t<4;t++){
          #pragma unroll
          for (int n=0;n<8;n++) acc[t][n] += d[t][e]*w8[n];
        }
      }
    }
    #pragma unroll
    for (int off=1; off<64; off<<=1){
      #pragma unroll
      for (int t=0;t<4;t++){
        #pragma unroll
        for (int n=0;n<8;n++) acc[t][n] += __shfl_xor(acc[t][n], off);
      }
    }
    if (l == 0){
      #pragma unroll
      for (int t=0;t<4;t++){
        #pragma unroll
        for (int n=0;n<8;n++) red[w*32 + t*8 + n] = acc[t][n];
      }
    }
    __syncthreads();
    if (tid < 64){
      int qd = tid >> 5, tn = tid & 31;
      int t = tn >> 3, n = tn & 7;
      float val = red[(qd*2)*32 + tn] + red[(qd*2+1)*32 + tn];
      int tok = bid*8 + qd*4 + t;
      int b = tok >> 11, s = tok & (S_-1);
      if (n < 4) igo[((size_t)(b*NH_+n))*S_ + s] = val + igb[n];
      else       fgo[((size_t)(b*NH_+(n-4)))*S_ + s] = val + fgb[n-4];
    }
  } else {
    int id = bid - 512;
    int sb = id & 31, db = (id >> 5) & 7, h = id >> 8;
    int b = h >> 2, n = h & 3;
    int s0 = sb*64, d0 = db*64;
    #pragma unroll
    for (int i=0;i<2;i++){
      int vv = tid + i*256; int r = vv>>3, c8 = vv&7;
      uint4 x = *(const uint4*)(v + (size_t)(b*S_+s0+r)*INNER_ + n*DH_ + d0 + c8*8);
      *(uint4*)&tl[r*LS + c8*8] = x;
    }
    __syncthreads();
    #pragma unroll
    for (int i=0;i<2;i++){
      int vv = tid + i*256; int r = vv>>3, c8 = vv&7;
      unsigned short tmp[8];
      #pragma unroll
      for (int e=0;e<8;e++) tmp[e] = (unsigned short)tl[(c8*8+e)*LS + r];
      uint4 o; __builtin_memcpy(&o, tmp, 16);
      *(uint4*)(vT + ((size_t)h*DH_ + d0 + r)*S_ + s0 + c8*8) = o;
    }
  }
}

// ---------------- per-head scan: F=cumsum(logsigmoid(fg)); a=ig-F; M=prefmax(a) ----
__global__ __launch_bounds__(256) void scan8(const float* __restrict__ igp,
    const float* __restrict__ fgp, float* __restrict__ ap,
    float* __restrict__ Mp, float* __restrict__ flp, float* __restrict__ rowsum){
  int h = blockIdx.x, tid = threadIdx.x;
  const float* fg = fgp + (size_t)h*S_;
  const float* ig = igp + (size_t)h*S_;
  int base = tid*8;
  float loc[8], run = 0.f;
  #pragma unroll
  for (int e=0;e<8;e++){
    float x = fg[base+e];
    float ls = fminf(x,0.f) - log1pf(expf(-fabsf(x)));
    run += ls; loc[e] = run;
  }
  __shared__ float sd[256];
  sd[tid]=run; __syncthreads();
  if (tid==0){ float r=0.f; for(int t=0;t<256;t++){ float t0=sd[t]; sd[t]=r; r+=t0; } }
  __syncthreads();
  float off = sd[tid];
  float lm[8], rm = -3e38f;
  #pragma unroll
  for (int e=0;e<8;e++){
    float F = loc[e]+off; loc[e]=F;
    float aj = ig[base+e]-F;
    ap[(size_t)h*S_+base+e]=aj;
    rm = fmaxf(rm, aj); lm[e]=rm;
  }
  __syncthreads();
  sd[tid]=rm; __syncthreads();
  if (tid==0){ float r=-3e38f; for(int t=0;t<256;t++){ float t0=sd[t]; sd[t]=r; r=fmaxf(r,t0); } }
  __syncthreads();
  float offm = sd[tid];
  #pragma unroll
  for (int e=0;e<8;e++){
    float M = fmaxf(lm[e], offm);
    Mp[(size_t)h*S_+base+e]=M;
    flp[(size_t)h*S_+base+e]=expf(-loc[e]-M);
    rowsum[(size_t)h*S_+base+e]=0.f;
  }
}

// ---------------- W = (Q K^T)*scale*exp(a_j - M_i), causal; + rowsums ----------------
// 64x128 i x j tiles, lower triangle; grid 8*272, h = bid&7 (XCD-pinned).
// Double-buffered d-tiles, stage-early + single __syncthreads per tile.
__global__ __launch_bounds__(256) void qk_decay_kernel(const bf16* __restrict__ qg,
    const bf16* __restrict__ kg, const float* __restrict__ ap,
    const float* __restrict__ Mp, float* __restrict__ rowsum, bf16* __restrict__ W){
  int h = blockIdx.x & 7;
  int t = 271 - (blockIdx.x >> 3);
  int p = (int)((sqrtf(4.f*t+1.f)-1.f)*0.5f);
  while ((p+1)*(p+2) <= t) p++;
  while (p*(p+1) > t) p--;
  int r0 = t - p*(p+1);
  int nj = p + 1;
  int it = 2*p + (r0 >= nj ? 1 : 0);
  int tj = r0 >= nj ? r0 - nj : r0;
  int b = h >> 2, n = h & 3;
  int i0 = it*64, j0 = tj*128;
  __shared__ __align__(16) short smem[2*12288];
  __shared__ float a_s[128], m_s[64];
  int tid = threadIdx.x;
  if (tid < 128) a_s[tid] = ap[(size_t)h*S_ + j0 + tid];
  if (tid < 64)  m_s[tid] = Mp[(size_t)h*S_ + i0 + tid];
  int w = tid>>6, l = tid&63, lq = l>>4, lr = l&15;
  int wm = (w>>1)*32, wn = (w&1)*64;
  const bf16* Qbase = qg + (size_t)(b*S_+i0)*INNER_ + n*DH_;
  const bf16* Kbase = kg + (size_t)(b*S_+j0)*INNER_ + n*DH_;
  floatx4 acc[2][4];
  #pragma unroll
  for (int mi=0;mi<2;mi++){
    #pragma unroll
    for (int ni=0;ni<4;ni++) acc[mi][ni] = (floatx4){0.f,0.f,0.f,0.f};
  }
  short* Qs0 = smem;          short* Ks0 = smem + 4096;
  short* Qs1 = smem + 12288;  short* Ks1 = smem + 16384;
  STAGE_ASYNC(Qs0, Qbase, INNER_, 0);
  STAGE_ASYNC(Qs0, Qbase, INNER_, 1);
  #pragma unroll
  for (int kk=0;kk<4;kk++){ STAGE_ASYNC(Ks0, Kbase, INNER_, kk); }
  __syncthreads();
  const int NT = DH_/64;   // 8
  for (int tt=0; tt<NT; ++tt){
    short* Qs  = (tt&1) ? Qs1 : Qs0;
    short* Ks  = (tt&1) ? Ks1 : Ks0;
    short* Qsn = (tt&1) ? Qs0 : Qs1;
    short* Ksn = (tt&1) ? Ks0 : Ks1;
    if (tt+1 < NT){
      int d0 = (tt+1)*64;
      STAGE_ASYNC(Qsn, Qbase + d0, INNER_, 0);
      STAGE_ASYNC(Qsn, Qbase + d0, INNER_, 1);
      #pragma unroll
      for (int kk=0;kk<4;kk++){ STAGE_ASYNC(Ksn, Kbase + d0, INNER_, kk); }
    }
    #pragma unroll
    for (int ks=0; ks<2; ks++){
      bf16x8 af[2], bfr[4];
      #pragma unroll
      for (int mi=0;mi<2;mi++) af[mi] = *(const bf16x8*)&Qs[so_(wm+mi*16+lr, ks*4+lq)];
      #pragma unroll
      for (int ni=0;ni<4;ni++) bfr[ni] = *(const bf16x8*)&Ks[so_(wn+ni*16+lr, ks*4+lq)];
      #pragma unroll
      for (int mi=0;mi<2;mi++){
        #pragma unroll
        for (int ni=0;ni<4;ni++)
          acc[mi][ni] = __builtin_amdgcn_mfma_f32_16x16x32_bf16(af[mi], bfr[ni], acc[mi][ni], 0,0,0);
      }
    }
    __syncthreads();
  }
  const float scale = 0.04419417382415922f;   // 1/sqrt(512)
  float rpart[2][4];
  #pragma unroll
  for (int mi=0;mi<2;mi++){
    #pragma unroll
    for (int r=0;r<4;r++) rpart[mi][r]=0.f;
  }
  #pragma unroll
  for (int mi=0;mi<2;mi++){
    #pragma unroll
    for (int ni=0;ni<4;ni++){
      int coll = wn + ni*16 + lr;
      int ch = coll>>3, off = coll&7;
      float av = a_s[coll];
      #pragma unroll
      for (int r=0;r<4;r++){
        int rowl = wm + mi*16 + lq*4 + r;
        int gi = i0 + rowl, gj = j0 + coll;
        float wv = 0.f;
        if (gj <= gi) wv = acc[mi][ni][r]*scale*__expf(av-m_s[rowl]);
        smem[rowl*128 + (((ch) ^ (rowl&15))<<3) + off] = (short)f2bu(wv);
        rpart[mi][r] += wv;
      }
    }
  }
  __syncthreads();
  #pragma unroll
  for (int i=0;i<4;i++){
    int slot = i*256 + tid;
    int r = slot >> 4, c8 = slot & 15;
    uint4 val = *(const uint4*)&smem[eo_(r, c8)];
    *(uint4*)(W + ((size_t)h*S_ + i0 + r)*S_ + j0 + c8*8) = val;
  }
  #pragma unroll
  for (int mi=0;mi<2;mi++){
    #pragma unroll
    for (int r=0;r<4;r++){
      float v = rpart[mi][r];
      v += __shfl_xor(v, 1, 16);
      v += __shfl_xor(v, 2, 16);
      v += __shfl_xor(v, 4, 16);
      v += __shfl_xor(v, 8, 16);
      if (lr == 0)
        atomicAdd(&rowsum[(size_t)h*S_ + i0 + wm + mi*16 + lq*4 + r], v);
    }
  }
}

// ---------------- O = (W * inv_row) @ V  (causal k-range), inv fused ----------------
// 64-row i-tiles x 128-d tiles: grid 8*128; h = bid&7 (XCD-pinned); ti descending.
__global__ __launch_bounds__(256) void pv_kernel(const bf16* __restrict__ W,
    const bf16* __restrict__ vT, const float* __restrict__ rowsum,
    const float* __restrict__ fl, bf16* __restrict__ O){
  int h = blockIdx.x & 7;
  int s = blockIdx.x >> 3;
  int ti = 31 - (s >> 2), tn = s & 3;
  int b = h >> 2, n = h & 3;
  int i0 = ti*64, d0 = tn*128;
  __shared__ __align__(16) short smem[2*12288];
  __shared__ float inv_s[64];
  int tid = threadIdx.x;
  if (tid < 64){
    size_t o = (size_t)h*S_ + i0 + tid;
    inv_s[tid] = 1.f/(fmaxf(fabsf(rowsum[o]), fl[o]) + EPS_CELL);
  }
  int w = tid>>6, l = tid&63, lq = l>>4, lr = l&15;
  int wm = (w>>1)*32, wn = (w&1)*64;
  const bf16* Wbase = W + ((size_t)h*S_ + i0)*S_;
  const bf16* Vbase = vT + ((size_t)h*DH_ + d0)*S_;
  floatx4 acc[2][4];
  #pragma unroll
  for (int mi=0;mi<2;mi++){
    #pragma unroll
    for (int ni=0;ni<4;ni++) acc[mi][ni] = (floatx4){0.f,0.f,0.f,0.f};
  }
  short* Ws0 = smem;          short* Vs0 = smem + 4096;
  short* Ws1 = smem + 12288;  short* Vs1 = smem + 16384;
  int NT = (i0 >> 6) + 1;
  STAGE_ASYNC(Ws0, Wbase, S_, 0);
  STAGE_ASYNC(Ws0, Wbase, S_, 1);
  #pragma unroll
  for (int kk=0;kk<4;kk++){ STAGE_ASYNC(Vs0, Vbase, S_, kk); }
  __syncthreads();
  for (int tt=0; tt<NT; ++tt){
    short* Ws  = (tt&1) ? Ws1 : Ws0;
    short* Vs  = (tt&1) ? Vs1 : Vs0;
    short* Wsn = (tt&1) ? Ws0 : Ws1;
    short* Vsn = (tt&1) ? Vs0 : Vs1;
    if (tt+1 < NT){
      int j0 = (tt+1)*64;
      STAGE_ASYNC(Wsn, Wbase + j0, S_, 0);
      STAGE_ASYNC(Wsn, Wbase + j0, S_, 1);
      #pragma unroll
      for (int kk=0;kk<4;kk++){ STAGE_ASYNC(Vsn, Vbase + j0, S_, kk); }
    }
    #pragma unroll
    for (int ks=0; ks<2; ks++){
      bf16x8 af[2], bfr[4];
      #pragma unroll
      for (int mi=0;mi<2;mi++) af[mi] = *(const bf16x8*)&Ws[so_(wm+mi*16+lr, ks*4+lq)];
      #pragma unroll
      for (int ni=0;ni<4;ni++) bfr[ni] = *(const bf16x8*)&Vs[so_(wn+ni*16+lr, ks*4+lq)];
      #pragma unroll
      for (int mi=0;mi<2;mi++){
        #pragma unroll
        for (int ni=0;ni<4;ni++)
          acc[mi][ni] = __builtin_amdgcn_mfma_f32_16x16x32_bf16(af[mi], bfr[ni], acc[mi][ni], 0,0,0);
      }
    }
    __syncthreads();
  }
  #pragma unroll
  for (int mi=0;mi<2;mi++){
    #pragma unroll
    for (int ni=0;ni<4;ni++){
      int dl = wn + ni*16 + lr;
      int ch = dl>>3, off = dl&7;
      #pragma unroll
      for (int r=0;r<4;r++){
        int rowl = wm + mi*16 + lq*4 + r;
        smem[rowl*128 + (((ch) ^ (rowl&15))<<3) + off] = (short)f2bu(acc[mi][ni][r] * inv_s[rowl]);
      }
    }
  }
  __syncthreads();
  #pragma unroll
  for (int i=0;i<4;i++){
    int slot = i*256 + tid;
    int r = slot >> 4, c8 = slot & 15;
    uint4 val = *(const uint4*)&smem[eo_(r, c8)];
    *(uint4*)(O + (size_t)(b*S_ + i0 + r)*INNER_ + n*DH_ + d0 + c8*8) = val;
  }
}

// ---------------- fused: w_down transpose (512 blocks) | headnorm+gate (16384) ----
__global__ __launch_bounds__(256) void headnorm_wdown(const bf16* __restrict__ h,
    const float* __restrict__ onw, const float* __restrict__ skip,
    const bf16* __restrict__ xca, bf16* __restrict__ up,
    const float* __restrict__ w_down, bf16* __restrict__ w_down_t){
  __shared__ float sa[256], sb[256];
  __shared__ float tl[64][65];
  int bid = blockIdx.x, tid = threadIdx.x;
  if (bid < 512){
    int n0 = (bid & 15)*64, k0 = (bid >> 4)*64;
    transpose_tile(w_down, w_down_t, INNER_, E_, n0, k0, tid, tl);
    return;
  }
  int id = bid - 512;
  int n = id & 3; int bs = id >> 2;
  size_t hbase = (size_t)bs*INNER_ + n*DH_;
  float v0 = b2f(h[hbase+tid]);
  float v1 = b2f(h[hbase+256+tid]);
  sa[tid]=v0+v1; sb[tid]=v0*v0+v1*v1;
  __syncthreads();
  for (int off=128; off>0; off>>=1){
    if (tid<off){ sa[tid]+=sa[tid+off]; sb[tid]+=sb[tid+off]; }
    __syncthreads();
  }
  float mean = sa[0]*(1.f/DH_);
  float var  = sb[0]*(1.f/DH_) - mean*mean;
  float rstd = rsqrtf(var + LN_EPS_);
  #pragma unroll
  for (int e=0;e<2;e++){
    int dl = e*256+tid; int c = n*DH_+dl;
    float hv = e ? v1 : v0;
    float hn = (hv-mean)*rstd*onw[c];
    float hs = hn + skip[c]*b2f(xca[(size_t)bs*INNER_+c]);
    size_t zoff = (size_t)bs*(2*INNER_) + INNER_ + c;
    float zv = b2f(up[zoff]);
    float sz = zv/(1.f+expf(-zv));
    up[zoff] = f2b(hs*sz);
  }
}

extern "C" void kernel_launch(void* const* d_in, const int* in_sizes, int n_in,
                              void* d_out, int out_size, void* d_ws, size_t ws_size,
                              hipStream_t stream) {
  const float* x      = (const float*)d_in[0];
  const float* w_in   = (const float*)d_in[1];
  const float* b_in   = (const float*)d_in[2];
  const float* ln1_w  = (const float*)d_in[3];
  const float* w_up   = (const float*)d_in[4];
  const float* b_up   = (const float*)d_in[5];
  const float* conv_w = (const float*)d_in[6];
  const float* conv_b = (const float*)d_in[7];
  const float* q_w    = (const float*)d_in[8];
  const float* q_b    = (const float*)d_in[9];
  const float* k_w    = (const float*)d_in[10];
  const float* k_b    = (const float*)d_in[11];
  const float* v_w    = (const float*)d_in[12];
  const float* v_b    = (const float*)d_in[13];
  const float* ig_w   = (const float*)d_in[14];
  const float* ig_b   = (const float*)d_in[15];
  const float* fg_w   = (const float*)d_in[16];
  const float* fg_b   = (const float*)d_in[17];
  const float* onw    = (const float*)d_in[18];
  const float* skip   = (const float*)d_in[19];
  const float* w_down = (const float*)d_in[20];
  const float* b_down = (const float*)d_in[21];
  const float* post_w = (const float*)d_in[22];

  char* p = (char*)d_ws;
  auto alloc = [&](size_t bytes)->void*{ void* r = p; p += (bytes + 255) & ~(size_t)255; return r; };
  bf16* h_in = (bf16*)alloc((size_t)T_*E_*2);        // 8 MB
  bf16* xn   = (bf16*)alloc((size_t)T_*E_*2);        // 8 MB (reused as y later)
  bf16* up   = (bf16*)alloc((size_t)T_*2*INNER_*2);  // 32 MB (x_m | z)
  bf16* xca  = (bf16*)alloc((size_t)T_*INNER_*2);    // 16 MB
  bf16* qb_  = (bf16*)alloc((size_t)T_*INNER_*2);
  bf16* kb_  = (bf16*)alloc((size_t)T_*INNER_*2);
  bf16* vb_  = (bf16*)alloc((size_t)T_*INNER_*2);    // v; later attention O
  bf16* hb_  = (bf16*)alloc((size_t)T_*INNER_*2);    // reused as vT (h,d,s)
  float* igbuf = (float*)alloc((size_t)B_*NH_*S_*4);
  float* fgbuf = (float*)alloc((size_t)B_*NH_*S_*4);
  float* abuf  = (float*)alloc((size_t)B_*NH_*S_*4);
  float* Mbuf  = (float*)alloc((size_t)B_*NH_*S_*4);
  float* flbuf = (float*)alloc((size_t)B_*NH_*S_*4);
  float* rsbuf = (float*)alloc((size_t)B_*NH_*S_*4);
  bf16* gwb  = (bf16*)alloc((size_t)3*INNER_*8*2);   // 96 KB packed gate weights
  bf16* Wbuf = (bf16*)alloc((size_t)B_*NH_*S_*S_*2); // 67 MB decay-weighted scores
  bf16* ybuf = xn;
  bf16* vTb  = hb_;
  bf16* obuf = vb_;
  bf16* xbf    = Wbuf;                               // 4 MB, dead after GEMM1
  bf16* w_in_t = Wbuf + (size_t)T_*IN_;              // 1 MB, dead after GEMM1
  bf16* w_up_t = w_in_t + (size_t)E_*IN_;            // 8 MB, dead after GEMM2
  bf16* w_down_t = Wbuf;                             // written AFTER pv frees Wbuf

  // 0. fused prep: convert x, transpose w_in/w_up, pack gate weights
  prep_fused<<<2200, 256, 0, stream>>>(x, w_in, w_up, ig_w, fg_w,
      xbf, w_in_t, w_up_t, gwb);
  // 1. h_in = x @ w_in + b_in   (64x128 tiles: 512 blocks)
  mfma_gemm64<<<(T_/64)*(E_/128), 256, 0, stream>>>(xbf, w_in_t, b_in, h_in, IN_, IN_, E_, E_/128);
  // 2. xn = LN(h_in)*ln1_w
  ln_rows<bf16><<<T_, 256, 0, stream>>>(h_in, nullptr, ln1_w, xn);
  // 3. up = xn @ w_up + b_up   (128x128: 1024 blocks)
  mfma_gemm<<<(T_/128)*((2*INNER_)/128), 256, 0, stream>>>(xn, w_up_t, b_up, up, E_, E_, 2*INNER_, (2*INNER_)/128);
  // 4+5. fused conv+SiLU and q/k/v projections
  conv_headwise<<<T_/CTB_, 256, 0, stream>>>(up, conv_w, conv_b,
      q_w, q_b, k_w, k_b, v_w, v_b, xca, qb_, kb_, vb_);
  // 6+8. fused gates GEMV + v->vT transpose
  gates_transv<<<512 + 2048, 256, 0, stream>>>(qb_, kb_, vb_, gwb, ig_b, fg_b,
      igbuf, fgbuf, vTb);
  // 7. scans: a, M, floor; zero rowsums
  scan8<<<B_*NH_, 256, 0, stream>>>(igbuf, fgbuf, abuf, Mbuf, flbuf, rsbuf);
  // 9. W = QK^T * scale * decay (64x128 lower-triangle tiles), rowsums
  qk_decay_kernel<<<8*272, 256, 0, stream>>>(qb_, kb_, abuf, Mbuf, rsbuf, Wbuf);
  // 10. O = (W*inv) @ V -> obuf
  pv_kernel<<<8*128, 256, 0, stream>>>(Wbuf, vTb, rsbuf, flbuf, obuf);
  // 11. fused: w_down transpose (Wbuf now dead) + headnorm/skip/gate into z
  headnorm_wdown<<<512 + T_*NH_, 256, 0, stream>>>(obuf, onw, skip, xca, up,
      w_down, w_down_t);
  // 12. y = h_gated @ w_down + b_down   (64x128 tiles: 512 blocks)
  mfma_gemm64<<<(T_/64)*(E_/128), 256, 0, stream>>>(up + INNER_, w_down_t, b_down, ybuf, INNER_, 2*INNER_, E_, E_/128);
  // 13. out = LN(h_in + y)*post_w
  ln_rows<float><<<T_, 256, 0, stream>>>(h_in, ybuf, post_w, (float*)d_out);
}

// Round 7
// 368.604 us; speedup vs baseline: 1.0903x; 1.0128x over previous
//
#include <hip/hip_runtime.h>
#include <hip/hip_bf16.h>

typedef __hip_bfloat16 bf16;
typedef float floatx4 __attribute__((ext_vector_type(4)));
typedef short bf16x8 __attribute__((ext_vector_type(8)));

#define B_      2
#define S_      2048
#define IN_     512
#define E_      1024
#define INNER_  2048
#define NH_     4
#define DH_     512
#define T_      (B_*S_)      // 4096 tokens
#define EPS_CELL 1e-6f
#define LN_EPS_  1e-5f
#define LS      72           // padded LDS row stride (shorts) for non-async kernels
#define CTB_    4            // tokens per block in conv_headwise

__device__ inline float b2f(bf16 x){ return __bfloat162float(x); }
__device__ inline bf16  f2b(float x){ return __float2bfloat16(x); }
__device__ inline float u2f(unsigned int u){ union{unsigned int i; float f;} v; v.i = u; return v.f; }
__device__ inline unsigned short f2bu(float x){ bf16 t = __float2bfloat16(x); unsigned short r; __builtin_memcpy(&r,&t,2); return r; }
__device__ inline void unpack8(uint4 u, float* f){
  f[0]=u2f(u.x<<16); f[1]=u2f(u.x&0xffff0000u);
  f[2]=u2f(u.y<<16); f[3]=u2f(u.y&0xffff0000u);
  f[4]=u2f(u.z<<16); f[5]=u2f(u.z&0xffff0000u);
  f[6]=u2f(u.w<<16); f[7]=u2f(u.w&0xffff0000u);
}
__device__ inline uint4 pack8(const float* f){
  uint4 u;
  u.x = (unsigned)f2bu(f[0]) | ((unsigned)f2bu(f[1])<<16);
  u.y = (unsigned)f2bu(f[2]) | ((unsigned)f2bu(f[3])<<16);
  u.z = (unsigned)f2bu(f[4]) | ((unsigned)f2bu(f[5])<<16);
  u.w = (unsigned)f2bu(f[6]) | ((unsigned)f2bu(f[7])<<16);
  return u;
}
__device__ inline void stv(bf16* p, float v){ *p = f2b(v); }
__device__ inline void stv(float* p, float v){ *p = v; }

// ---- async 16B global->LDS copy (wave-uniform base + lane*16 pattern) ----
typedef __attribute__((address_space(3))) unsigned int lds_u32_t;
typedef __attribute__((address_space(1))) const unsigned int glb_u32_t;
__device__ __forceinline__ void cp_async16(const bf16* g, short* l){
  __builtin_amdgcn_global_load_lds((glb_u32_t*)(const void*)g,
                                   (lds_u32_t*)(void*)l, 16, 0, 0);
}
// swizzled LDS offset (shorts) for Nx64 tile: row-dense, chunk XOR row&7
__device__ __forceinline__ int so_(int row, int c8){ return row*64 + (((c8) ^ (row&7))<<3); }
// epilogue repack offset for Nx128-short tile: chunk XOR row&15
__device__ __forceinline__ int eo_(int row, int ch){ return row*128 + (((ch) ^ (row&15))<<3); }

// stage rows of a tile with 256 threads (row stride `stride` in global)
#define STAGE_ASYNC(dst, srcbase, stride, kk) \
  { int slot_ = (kk)*256 + tid; int r_ = slot_>>3; int c8_ = (slot_&7) ^ (r_&7); \
    cp_async16((srcbase) + (size_t)r_*(stride) + c8_*8, &dst[slot_*8]); }

// stage with 512 threads
#define STAGE_ASYNC5(dst, srcbase, stride, kk) \
  { int slot_ = (kk)*512 + tid; int r_ = slot_>>3; int c8_ = (slot_&7) ^ (r_&7); \
    cp_async16((srcbase) + (size_t)r_*(stride) + c8_*8, &dst[slot_*8]); }

// ---------------- W[K,N] fp32 -> Wt[N,K] bf16 (64x64 LDS tile), device body ----
__device__ inline void transpose_tile(const float* W, bf16* Wt, int K, int N,
    int n0, int k0, int tid, float (*tl)[65]){
  #pragma unroll
  for (int i=0;i<4;i++){
    int idx = tid + i*256; int r = idx>>4, c4 = idx&15;
    float4 v = *(const float4*)(W + (size_t)(k0+r)*N + n0 + c4*4);
    tl[r][c4*4+0]=v.x; tl[r][c4*4+1]=v.y; tl[r][c4*4+2]=v.z; tl[r][c4*4+3]=v.w;
  }
  __syncthreads();
  #pragma unroll
  for (int i=0;i<4;i++){
    int idx = tid + i*256; int rn = idx>>4, c4 = idx&15;
    ushort4 o;
    o.x=f2bu(tl[c4*4+0][rn]); o.y=f2bu(tl[c4*4+1][rn]);
    o.z=f2bu(tl[c4*4+2][rn]); o.w=f2bu(tl[c4*4+3][rn]);
    *(ushort4*)(Wt + (size_t)(n0+rn)*K + k0 + c4*4) = o;
  }
}

// ---------------- fused prep: convert x | transpose w_in | transpose w_up | pack gates ----
__global__ __launch_bounds__(256) void prep_fused(const float* __restrict__ x,
    const float* __restrict__ w_in, const float* __restrict__ w_up,
    const float* __restrict__ igw, const float* __restrict__ fgw,
    bf16* __restrict__ xbf, bf16* __restrict__ w_in_t, bf16* __restrict__ w_up_t,
    bf16* __restrict__ gwb){
  __shared__ float tl[64][65];
  int bid = blockIdx.x, tid = threadIdx.x;
  if (bid < 1024){
    int i = bid*256 + tid;
    const float4* p = (const float4*)(x) + i*2;
    float4 a = p[0], b = p[1];
    ushort4 o0, o1;
    o0.x=f2bu(a.x); o0.y=f2bu(a.y); o0.z=f2bu(a.z); o0.w=f2bu(a.w);
    o1.x=f2bu(b.x); o1.y=f2bu(b.y); o1.z=f2bu(b.z); o1.w=f2bu(b.w);
    ushort4* q = (ushort4*)(xbf) + i*2;
    q[0]=o0; q[1]=o1;
  } else if (bid < 1152){
    int id = bid - 1024;
    int n0 = (id & 15)*64, k0 = (id >> 4)*64;
    transpose_tile(w_in, w_in_t, IN_, E_, n0, k0, tid, tl);
  } else if (bid < 2176){
    int id = bid - 1152;
    int n0 = (id & 63)*64, k0 = (id >> 6)*64;
    transpose_tile(w_up, w_up_t, E_, 2*INNER_, n0, k0, tid, tl);
  } else {
    int idx = (bid - 2176)*256 + tid;
    if (idx < 3*INNER_){
      int g = idx >> 9;
      int e = (idx >> 6) & 7;
      int l = idx & 63;
      int r = g*512 + l*8 + e;
      float4 a = *(const float4*)(igw + (size_t)r*4);
      float4 b = *(const float4*)(fgw + (size_t)r*4);
      ushort4 o0, o1;
      o0.x=f2bu(a.x); o0.y=f2bu(a.y); o0.z=f2bu(a.z); o0.w=f2bu(a.w);
      o1.x=f2bu(b.x); o1.y=f2bu(b.y); o1.z=f2bu(b.z); o1.w=f2bu(b.w);
      *(ushort4*)(gwb + (size_t)idx*8)     = o0;
      *(ushort4*)(gwb + (size_t)idx*8 + 4) = o1;
    }
  }
}

// ---------------- MFMA GEMM 128x128: C = A @ Bt^T + bias ----------------
__global__ __launch_bounds__(256) void mfma_gemm(const bf16* __restrict__ A,
    const bf16* __restrict__ Bt, const float* __restrict__ bias, bf16* __restrict__ C,
    int Kd, int lda, int ldc, int NN){
  int bid = blockIdx.x;
  int MM = gridDim.x / NN;
  int mPerX = MM >> 3;
  int xcd = bid & 7, seq = bid >> 3;
  int nb = seq % NN, mb = xcd*mPerX + seq / NN;
  int n0 = nb*128, m0 = mb*128;
  __shared__ __align__(16) short smem[32768];
  int tid = threadIdx.x;
  int w = tid>>6, l = tid&63, lq = l>>4, lr = l&15;
  int wm = (w>>1)*64, wn = (w&1)*64;
  const bf16* Abase = A + (size_t)m0*lda;
  const bf16* Bbase = Bt + (size_t)n0*Kd;
  floatx4 acc[4][4];
  #pragma unroll
  for (int mi=0;mi<4;mi++){
    #pragma unroll
    for (int ni=0;ni<4;ni++) acc[mi][ni] = (floatx4){0.f,0.f,0.f,0.f};
  }
  short* As0 = smem;          short* Bs0 = smem + 8192;
  short* As1 = smem + 16384;  short* Bs1 = smem + 24576;
  int NT = Kd >> 6;
  #pragma unroll
  for (int kk=0;kk<4;kk++){
    STAGE_ASYNC(As0, Abase, lda, kk);
    STAGE_ASYNC(Bs0, Bbase, Kd, kk);
  }
  __syncthreads();
  for (int t=0; t<NT; ++t){
    short* As  = (t&1) ? As1 : As0;
    short* Bs  = (t&1) ? Bs1 : Bs0;
    short* Asn = (t&1) ? As0 : As1;
    short* Bsn = (t&1) ? Bs0 : Bs1;
    if (t+1 < NT){
      int k0 = (t+1)*64;
      #pragma unroll
      for (int kk=0;kk<4;kk++){
        STAGE_ASYNC(Asn, Abase + k0, lda, kk);
        STAGE_ASYNC(Bsn, Bbase + k0, Kd, kk);
      }
    }
    #pragma unroll
    for (int ks=0; ks<2; ks++){
      bf16x8 af[4], bfr[4];
      #pragma unroll
      for (int mi=0;mi<4;mi++) af[mi] = *(const bf16x8*)&As[so_(wm+mi*16+lr, ks*4+lq)];
      #pragma unroll
      for (int ni=0;ni<4;ni++) bfr[ni] = *(const bf16x8*)&Bs[so_(wn+ni*16+lr, ks*4+lq)];
      #pragma unroll
      for (int mi=0;mi<4;mi++){
        #pragma unroll
        for (int ni=0;ni<4;ni++)
          acc[mi][ni] = __builtin_amdgcn_mfma_f32_16x16x32_bf16(af[mi], bfr[ni], acc[mi][ni], 0,0,0);
      }
    }
    __syncthreads();
  }
  float bb[4];
  #pragma unroll
  for (int ni=0;ni<4;ni++) bb[ni] = bias[n0 + wn + ni*16 + lr];
  #pragma unroll
  for (int mi=0;mi<4;mi++){
    #pragma unroll
    for (int ni=0;ni<4;ni++){
      int coll = wn + ni*16 + lr;
      int ch = coll>>3, off = coll&7;
      #pragma unroll
      for (int r=0;r<4;r++){
        int rowl = wm + mi*16 + lq*4 + r;
        smem[rowl*128 + (((ch) ^ (rowl&15))<<3) + off] = (short)f2bu(acc[mi][ni][r] + bb[ni]);
      }
    }
  }
  __syncthreads();
  #pragma unroll
  for (int i=0;i<8;i++){
    int slot = i*256 + tid;
    int r = slot >> 4, c8 = slot & 15;
    uint4 val = *(const uint4*)&smem[eo_(r, c8)];
    *(uint4*)(C + (size_t)(m0+r)*ldc + n0 + c8*8) = val;
  }
}

// ---------------- MFMA GEMM 64x128 tile (for N=1024 GEMMs: 512 blocks = 2/CU) ----
__global__ __launch_bounds__(256) void mfma_gemm64(const bf16* __restrict__ A,
    const bf16* __restrict__ Bt, const float* __restrict__ bias, bf16* __restrict__ C,
    int Kd, int lda, int ldc, int NN){
  int bid = blockIdx.x;
  int MM = gridDim.x / NN;
  int mPerX = MM >> 3;
  int xcd = bid & 7, seq = bid >> 3;
  int nb = seq % NN, mb = xcd*mPerX + seq / NN;
  int n0 = nb*128, m0 = mb*64;
  __shared__ __align__(16) short smem[24576];
  int tid = threadIdx.x;
  int w = tid>>6, l = tid&63, lq = l>>4, lr = l&15;
  int wm = (w>>1)*32, wn = (w&1)*64;
  const bf16* Abase = A + (size_t)m0*lda;
  const bf16* Bbase = Bt + (size_t)n0*Kd;
  floatx4 acc[2][4];
  #pragma unroll
  for (int mi=0;mi<2;mi++){
    #pragma unroll
    for (int ni=0;ni<4;ni++) acc[mi][ni] = (floatx4){0.f,0.f,0.f,0.f};
  }
  short* As0 = smem;          short* Bs0 = smem + 4096;
  short* As1 = smem + 12288;  short* Bs1 = smem + 16384;
  int NT = Kd >> 6;
  STAGE_ASYNC(As0, Abase, lda, 0);
  STAGE_ASYNC(As0, Abase, lda, 1);
  #pragma unroll
  for (int kk=0;kk<4;kk++){ STAGE_ASYNC(Bs0, Bbase, Kd, kk); }
  __syncthreads();
  for (int t=0; t<NT; ++t){
    short* As  = (t&1) ? As1 : As0;
    short* Bs  = (t&1) ? Bs1 : Bs0;
    short* Asn = (t&1) ? As0 : As1;
    short* Bsn = (t&1) ? Bs0 : Bs1;
    if (t+1 < NT){
      int k0 = (t+1)*64;
      STAGE_ASYNC(Asn, Abase + k0, lda, 0);
      STAGE_ASYNC(Asn, Abase + k0, lda, 1);
      #pragma unroll
      for (int kk=0;kk<4;kk++){ STAGE_ASYNC(Bsn, Bbase + k0, Kd, kk); }
    }
    #pragma unroll
    for (int ks=0; ks<2; ks++){
      bf16x8 af[2], bfr[4];
      #pragma unroll
      for (int mi=0;mi<2;mi++) af[mi] = *(const bf16x8*)&As[so_(wm+mi*16+lr, ks*4+lq)];
      #pragma unroll
      for (int ni=0;ni<4;ni++) bfr[ni] = *(const bf16x8*)&Bs[so_(wn+ni*16+lr, ks*4+lq)];
      #pragma unroll
      for (int mi=0;mi<2;mi++){
        #pragma unroll
        for (int ni=0;ni<4;ni++)
          acc[mi][ni] = __builtin_amdgcn_mfma_f32_16x16x32_bf16(af[mi], bfr[ni], acc[mi][ni], 0,0,0);
      }
    }
    __syncthreads();
  }
  float bb[4];
  #pragma unroll
  for (int ni=0;ni<4;ni++) bb[ni] = bias[n0 + wn + ni*16 + lr];
  #pragma unroll
  for (int mi=0;mi<2;mi++){
    #pragma unroll
    for (int ni=0;ni<4;ni++){
      int coll = wn + ni*16 + lr;
      int ch = coll>>3, off = coll&7;
      #pragma unroll
      for (int r=0;r<4;r++){
        int rowl = wm + mi*16 + lq*4 + r;
        smem[rowl*128 + (((ch) ^ (rowl&15))<<3) + off] = (short)f2bu(acc[mi][ni][r] + bb[ni]);
      }
    }
  }
  __syncthreads();
  #pragma unroll
  for (int i=0;i<4;i++){
    int slot = i*256 + tid;
    int r = slot >> 4, c8 = slot & 15;
    uint4 val = *(const uint4*)&smem[eo_(r, c8)];
    *(uint4*)(C + (size_t)(m0+r)*ldc + n0 + c8*8) = val;
  }
}

// ---------------- layernorm over rows of length E_ (opt. fused add) ----------------
template<typename OutT>
__global__ __launch_bounds__(256) void ln_rows(const bf16* __restrict__ X,
    const bf16* __restrict__ Xadd, const float* __restrict__ w, OutT* __restrict__ Y){
  int row = blockIdx.x, tid = threadIdx.x;
  size_t base = (size_t)row*E_;
  float vals[4], s=0.f, s2=0.f;
  #pragma unroll
  for (int e=0;e<4;e++){
    int c = e*256+tid;
    float v = b2f(X[base+c]);
    if (Xadd) v += b2f(Xadd[base+c]);
    vals[e]=v; s+=v; s2+=v*v;
  }
  __shared__ float sa[256], sb[256];
  sa[tid]=s; sb[tid]=s2; __syncthreads();
  for (int off=128; off>0; off>>=1){
    if (tid<off){ sa[tid]+=sa[tid+off]; sb[tid]+=sb[tid+off]; }
    __syncthreads();
  }
  float mean = sa[0]*(1.f/E_);
  float var  = sb[0]*(1.f/E_) - mean*mean;
  float rstd = rsqrtf(var + LN_EPS_);
  #pragma unroll
  for (int e=0;e<4;e++){
    int c = e*256+tid;
    stv(&Y[base+c], (vals[e]-mean)*rstd*w[c]);
  }
}

// ---------------- fused causal conv(K=4)+SiLU and block-diagonal q/k/v ----------------
__global__ __launch_bounds__(256) void conv_headwise(const bf16* __restrict__ up,
    const float* __restrict__ cw, const float* __restrict__ cb,
    const float* __restrict__ qw, const float* __restrict__ qb,
    const float* __restrict__ kw, const float* __restrict__ kb,
    const float* __restrict__ vw, const float* __restrict__ vb,
    bf16* __restrict__ xca, bf16* __restrict__ q, bf16* __restrict__ k,
    bf16* __restrict__ v){
  int t0 = blockIdx.x*CTB_;
  int s0 = t0 & (S_-1);
  int c0 = threadIdx.x*8;
  int hw0 = c0 >> 2;

  float row[7][8];
  #pragma unroll
  for (int j=0;j<7;j++){
    if (s0-3+j >= 0){
      uint4 rv = *(const uint4*)(up + (size_t)(t0-3+j)*(2*INNER_) + c0);
      unpack8(rv, row[j]);
    } else {
      #pragma unroll
      for (int e=0;e<8;e++) row[j][e]=0.f;
    }
  }

  float xc[CTB_][8];
  {
    float cwv[8][4], cbv[8];
    #pragma unroll
    for (int e=0;e<8;e++){
      float4 w4 = *(const float4*)(cw + (size_t)(c0+e)*4);
      cwv[e][0]=w4.x; cwv[e][1]=w4.y; cwv[e][2]=w4.z; cwv[e][3]=w4.w;
    }
    float4 b0 = *(const float4*)(cb+c0), b1 = *(const float4*)(cb+c0+4);
    cbv[0]=b0.x; cbv[1]=b0.y; cbv[2]=b0.z; cbv[3]=b0.w;
    cbv[4]=b1.x; cbv[5]=b1.y; cbv[6]=b1.z; cbv[7]=b1.w;
    #pragma unroll
    for (int i=0;i<CTB_;i++){
      #pragma unroll
      for (int e=0;e<8;e++){
        float a = cbv[e];
        #pragma unroll
        for (int t=0;t<4;t++) a += row[i+t][e]*cwv[e][t];
        xc[i][e] = a/(1.f+expf(-a));
      }
      *(uint4*)(xca + (size_t)(t0+i)*INNER_ + c0) = pack8(xc[i]);
    }
  }

  {
    float wv_[32], bv[8];
    #pragma unroll
    for (int g=0;g<2;g++){
      #pragma unroll
      for (int r4=0;r4<4;r4++){
        float4 w4 = *(const float4*)(vw + (size_t)(hw0+g)*16 + r4*4);
        wv_[g*16+r4*4+0]=w4.x; wv_[g*16+r4*4+1]=w4.y;
        wv_[g*16+r4*4+2]=w4.z; wv_[g*16+r4*4+3]=w4.w;
      }
    }
    float4 b0 = *(const float4*)(vb+c0), b1 = *(const float4*)(vb+c0+4);
    bv[0]=b0.x; bv[1]=b0.y; bv[2]=b0.z; bv[3]=b0.w;
    bv[4]=b1.x; bv[5]=b1.y; bv[6]=b1.z; bv[7]=b1.w;
    #pragma unroll
    for (int i=0;i<CTB_;i++){
      float ov[8];
      #pragma unroll
      for (int g=0;g<2;g++){
        #pragma unroll
        for (int o=0;o<4;o++){
          float a = bv[g*4+o];
          #pragma unroll
          for (int d=0;d<4;d++) a += row[i+3][g*4+d]*wv_[g*16+o*4+d];
          ov[g*4+o]=a;
        }
      }
      *(uint4*)(v + (size_t)(t0+i)*INNER_ + c0) = pack8(ov);
    }
  }

  {
    float wv_[32], bv[8];
    #pragma unroll
    for (int g=0;g<2;g++){
      #pragma unroll
      for (int r4=0;r4<4;r4++){
        float4 w4 = *(const float4*)(qw + (size_t)(hw0+g)*16 + r4*4);
        wv_[g*16+r4*4+0]=w4.x; wv_[g*16+r4*4+1]=w4.y;
        wv_[g*16+r4*4+2]=w4.z; wv_[g*16+r4*4+3]=w4.w;
      }
    }
    float4 b0 = *(const float4*)(qb+c0), b1 = *(const float4*)(qb+c0+4);
    bv[0]=b0.x; bv[1]=b0.y; bv[2]=b0.z; bv[3]=b0.w;
    bv[4]=b1.x; bv[5]=b1.y; bv[6]=b1.z; bv[7]=b1.w;
    #pragma unroll
    for (int i=0;i<CTB_;i++){
      float ov[8];
      #pragma unroll
      for (int g=0;g<2;g++){
        #pragma unroll
        for (int o=0;o<4;o++){
          float a = bv[g*4+o];
          #pragma unroll
          for (int d=0;d<4;d++) a += xc[i][g*4+d]*wv_[g*16+o*4+d];
          ov[g*4+o]=a;
        }
      }
      *(uint4*)(q + (size_t)(t0+i)*INNER_ + c0) = pack8(ov);
    }
  }

  {
    float wv_[32], bv[8];
    #pragma unroll
    for (int g=0;g<2;g++){
      #pragma unroll
      for (int r4=0;r4<4;r4++){
        float4 w4 = *(const float4*)(kw + (size_t)(hw0+g)*16 + r4*4);
        wv_[g*16+r4*4+0]=w4.x; wv_[g*16+r4*4+1]=w4.y;
        wv_[g*16+r4*4+2]=w4.z; wv_[g*16+r4*4+3]=w4.w;
      }
    }
    float4 b0 = *(const float4*)(kb+c0), b1 = *(const float4*)(kb+c0+4);
    bv[0]=b0.x; bv[1]=b0.y; bv[2]=b0.z; bv[3]=b0.w;
    bv[4]=b1.x; bv[5]=b1.y; bv[6]=b1.z; bv[7]=b1.w;
    #pragma unroll
    for (int i=0;i<CTB_;i++){
      float ov[8];
      #pragma unroll
      for (int g=0;g<2;g++){
        #pragma unroll
        for (int o=0;o<4;o++){
          float a = bv[g*4+o];
          #pragma unroll
          for (int d=0;d<4;d++) a += xc[i][g*4+d]*wv_[g*16+o*4+d];
          ov[g*4+o]=a;
        }
      }
      *(uint4*)(k + (size_t)(t0+i)*INNER_ + c0) = pack8(ov);
    }
  }
}

// ---------------- fused: gates GEMV (512 blocks) | v->vT transpose (2048 blocks) ----
__global__ __launch_bounds__(256) void gates_transv(const bf16* __restrict__ q,
    const bf16* __restrict__ k, const bf16* __restrict__ v,
    const bf16* __restrict__ gwb, const float* __restrict__ igb,
    const float* __restrict__ fgb, float* __restrict__ igo, float* __restrict__ fgo,
    bf16* __restrict__ vT){
  __shared__ float red[4*32];
  __shared__ short tl[64*LS];
  int bid = blockIdx.x, tid = threadIdx.x;
  if (bid < 512){
    int w = tid >> 6, l = tid & 63;
    int quad = w >> 1, kh = w & 1;
    int tok0 = bid*8 + quad*4;
    float acc[4][8];
    #pragma unroll
    for (int t=0;t<4;t++){
      #pragma unroll
      for (int n=0;n<8;n++) acc[t][n]=0.f;
    }
    #pragma unroll 2
    for (int it=0; it<6; ++it){
      int src = it >> 1, j = it & 1;
      const bf16* sp = (src==0) ? q : ((src==1) ? k : v);
      int pos = kh*1024 + j*512 + l*8;
      int g = src*4 + kh*2 + j;
      uint4 dv[4];
      #pragma unroll
      for (int t=0;t<4;t++)
        dv[t] = *(const uint4*)(sp + (size_t)(tok0+t)*INNER_ + pos);
      float d[4][8];
      #pragma unroll
      for (int t=0;t<4;t++) unpack8(dv[t], d[t]);
      const bf16* wb = gwb + (size_t)g*512*8;
      #pragma unroll
      for (int e=0;e<8;e++){
        uint4 wv = *(const uint4*)(wb + (size_t)(e*64 + l)*8);
        float w8[8]; unpack8(wv, w8);
        #pragma unroll
        for (int t=0;t<4;t++){
          #pragma unroll
          for (int n=0;n<8;n++) acc[t][n] += d[t][e]*w8[n];
        }
      }
    }
    #pragma unroll
    for (int off=1; off<64; off<<=1){
      #pragma unroll
      for (int t=0;t<4;t++){
        #pragma unroll
        for (int n=0;n<8;n++) acc[t][n] += __shfl_xor(acc[t][n], off);
      }
    }
    if (l == 0){
      #pragma unroll
      for (int t=0;t<4;t++){
        #pragma unroll
        for (int n=0;n<8;n++) red[w*32 + t*8 + n] = acc[t][n];
      }
    }
    __syncthreads();
    if (tid < 64){
      int qd = tid >> 5, tn = tid & 31;
      int t = tn >> 3, n = tn & 7;
      float val = red[(qd*2)*32 + tn] + red[(qd*2+1)*32 + tn];
      int tok = bid*8 + qd*4 + t;
      int b = tok >> 11, s = tok & (S_-1);
      if (n < 4) igo[((size_t)(b*NH_+n))*S_ + s] = val + igb[n];
      else       fgo[((size_t)(b*NH_+(n-4)))*S_ + s] = val + fgb[n-4];
    }
  } else {
    int id = bid - 512;
    int sb = id & 31, db = (id >> 5) & 7, h = id >> 8;
    int b = h >> 2, n = h & 3;
    int s0 = sb*64, d0 = db*64;
    #pragma unroll
    for (int i=0;i<2;i++){
      int vv = tid + i*256; int r = vv>>3, c8 = vv&7;
      uint4 x = *(const uint4*)(v + (size_t)(b*S_+s0+r)*INNER_ + n*DH_ + d0 + c8*8);
      *(uint4*)&tl[r*LS + c8*8] = x;
    }
    __syncthreads();
    #pragma unroll
    for (int i=0;i<2;i++){
      int vv = tid + i*256; int r = vv>>3, c8 = vv&7;
      unsigned short tmp[8];
      #pragma unroll
      for (int e=0;e<8;e++) tmp[e] = (unsigned short)tl[(c8*8+e)*LS + r];
      uint4 o; __builtin_memcpy(&o, tmp, 16);
      *(uint4*)(vT + ((size_t)h*DH_ + d0 + r)*S_ + s0 + c8*8) = o;
    }
  }
}

// ---------------- per-head scan: F=cumsum(logsigmoid(fg)); a=ig-F; M=prefmax(a) ----
__global__ __launch_bounds__(256) void scan8(const float* __restrict__ igp,
    const float* __restrict__ fgp, float* __restrict__ ap,
    float* __restrict__ Mp, float* __restrict__ flp, float* __restrict__ rowsum){
  int h = blockIdx.x, tid = threadIdx.x;
  const float* fg = fgp + (size_t)h*S_;
  const float* ig = igp + (size_t)h*S_;
  int base = tid*8;
  float loc[8], run = 0.f;
  #pragma unroll
  for (int e=0;e<8;e++){
    float x = fg[base+e];
    float ls = fminf(x,0.f) - log1pf(expf(-fabsf(x)));
    run += ls; loc[e] = run;
  }
  __shared__ float sd[256];
  sd[tid]=run; __syncthreads();
  if (tid==0){ float r=0.f; for(int t=0;t<256;t++){ float t0=sd[t]; sd[t]=r; r+=t0; } }
  __syncthreads();
  float off = sd[tid];
  float lm[8], rm = -3e38f;
  #pragma unroll
  for (int e=0;e<8;e++){
    float F = loc[e]+off; loc[e]=F;
    float aj = ig[base+e]-F;
    ap[(size_t)h*S_+base+e]=aj;
    rm = fmaxf(rm, aj); lm[e]=rm;
  }
  __syncthreads();
  sd[tid]=rm; __syncthreads();
  if (tid==0){ float r=-3e38f; for(int t=0;t<256;t++){ float t0=sd[t]; sd[t]=r; r=fmaxf(r,t0); } }
  __syncthreads();
  float offm = sd[tid];
  #pragma unroll
  for (int e=0;e<8;e++){
    float M = fmaxf(lm[e], offm);
    Mp[(size_t)h*S_+base+e]=M;
    flp[(size_t)h*S_+base+e]=expf(-loc[e]-M);
    rowsum[(size_t)h*S_+base+e]=0.f;
  }
}

// ---------------- W = (Q K^T)*scale*exp(a_j - M_i), causal; + rowsums ----------------
// 64x128 i x j tiles, lower triangle; grid 8*272, h = bid&7 (XCD-pinned).
// 512 threads = 8 waves (4 i-groups x 2 j-groups); 2-phase double-buffer.
__global__ __launch_bounds__(512) void qk_decay_kernel(const bf16* __restrict__ qg,
    const bf16* __restrict__ kg, const float* __restrict__ ap,
    const float* __restrict__ Mp, float* __restrict__ rowsum, bf16* __restrict__ W){
  int h = blockIdx.x & 7;
  int t = 271 - (blockIdx.x >> 3);
  int p = (int)((sqrtf(4.f*t+1.f)-1.f)*0.5f);
  while ((p+1)*(p+2) <= t) p++;
  while (p*(p+1) > t) p--;
  int r0 = t - p*(p+1);
  int nj = p + 1;
  int it = 2*p + (r0 >= nj ? 1 : 0);
  int tj = r0 >= nj ? r0 - nj : r0;
  int b = h >> 2, n = h & 3;
  int i0 = it*64, j0 = tj*128;
  __shared__ __align__(16) short smem[2*12288];
  __shared__ float a_s[128], m_s[64];
  int tid = threadIdx.x;
  if (tid < 128) a_s[tid] = ap[(size_t)h*S_ + j0 + tid];
  if (tid < 64)  m_s[tid] = Mp[(size_t)h*S_ + i0 + tid];
  int w = tid>>6, l = tid&63, lq = l>>4, lr = l&15;
  int wm = (w>>1)*16, wn = (w&1)*64;
  const bf16* Qbase = qg + (size_t)(b*S_+i0)*INNER_ + n*DH_;
  const bf16* Kbase = kg + (size_t)(b*S_+j0)*INNER_ + n*DH_;
  floatx4 acc[4];
  #pragma unroll
  for (int ni=0;ni<4;ni++) acc[ni] = (floatx4){0.f,0.f,0.f,0.f};
  short* Qs0 = smem;          short* Ks0 = smem + 4096;
  short* Qs1 = smem + 12288;  short* Ks1 = smem + 16384;
  STAGE_ASYNC5(Qs0, Qbase, INNER_, 0);
  STAGE_ASYNC5(Ks0, Kbase, INNER_, 0);
  STAGE_ASYNC5(Ks0, Kbase, INNER_, 1);
  __syncthreads();
  const int NT = DH_/64;   // 8
  for (int tt=0; tt<NT; ++tt){
    short* Qs  = (tt&1) ? Qs1 : Qs0;
    short* Ks  = (tt&1) ? Ks1 : Ks0;
    short* Qsn = (tt&1) ? Qs0 : Qs1;
    short* Ksn = (tt&1) ? Ks0 : Ks1;
    if (tt+1 < NT){
      int d0 = (tt+1)*64;
      STAGE_ASYNC5(Qsn, Qbase + d0, INNER_, 0);
      STAGE_ASYNC5(Ksn, Kbase + d0, INNER_, 0);
      STAGE_ASYNC5(Ksn, Kbase + d0, INNER_, 1);
    }
    #pragma unroll
    for (int ks=0; ks<2; ks++){
      bf16x8 af, bfr[4];
      af = *(const bf16x8*)&Qs[so_(wm+lr, ks*4+lq)];
      #pragma unroll
      for (int ni=0;ni<4;ni++) bfr[ni] = *(const bf16x8*)&Ks[so_(wn+ni*16+lr, ks*4+lq)];
      #pragma unroll
      for (int ni=0;ni<4;ni++)
        acc[ni] = __builtin_amdgcn_mfma_f32_16x16x32_bf16(af, bfr[ni], acc[ni], 0,0,0);
    }
    __syncthreads();
  }
  const float scale = 0.04419417382415922f;   // 1/sqrt(512)
  float rpart[4];
  #pragma unroll
  for (int r=0;r<4;r++) rpart[r]=0.f;
  #pragma unroll
  for (int ni=0;ni<4;ni++){
    int coll = wn + ni*16 + lr;
    int ch = coll>>3, off = coll&7;
    float av = a_s[coll];
    #pragma unroll
    for (int r=0;r<4;r++){
      int rowl = wm + lq*4 + r;
      int gi = i0 + rowl, gj = j0 + coll;
      float wv = 0.f;
      if (gj <= gi) wv = acc[ni][r]*scale*__expf(av-m_s[rowl]);
      smem[rowl*128 + (((ch) ^ (rowl&15))<<3) + off] = (short)f2bu(wv);
      rpart[r] += wv;
    }
  }
  __syncthreads();
  #pragma unroll
  for (int i=0;i<2;i++){
    int slot = i*512 + tid;
    int r = slot >> 4, c8 = slot & 15;
    uint4 val = *(const uint4*)&smem[eo_(r, c8)];
    *(uint4*)(W + ((size_t)h*S_ + i0 + r)*S_ + j0 + c8*8) = val;
  }
  #pragma unroll
  for (int r=0;r<4;r++){
    float v = rpart[r];
    v += __shfl_xor(v, 1, 16);
    v += __shfl_xor(v, 2, 16);
    v += __shfl_xor(v, 4, 16);
    v += __shfl_xor(v, 8, 16);
    if (lr == 0)
      atomicAdd(&rowsum[(size_t)h*S_ + i0 + wm + lq*4 + r], v);
  }
}

// ---------------- O = (W * inv_row) @ V  (causal k-range), inv fused ----------------
// 64-row i-tiles x 128-d tiles: grid 8*128; 512 threads = 8 waves.
__global__ __launch_bounds__(512) void pv_kernel(const bf16* __restrict__ W,
    const bf16* __restrict__ vT, const float* __restrict__ rowsum,
    const float* __restrict__ fl, bf16* __restrict__ O){
  int h = blockIdx.x & 7;
  int s = blockIdx.x >> 3;
  int ti = 31 - (s >> 2), tn = s & 3;
  int b = h >> 2, n = h & 3;
  int i0 = ti*64, d0 = tn*128;
  __shared__ __align__(16) short smem[2*12288];
  __shared__ float inv_s[64];
  int tid = threadIdx.x;
  if (tid < 64){
    size_t o = (size_t)h*S_ + i0 + tid;
    inv_s[tid] = 1.f/(fmaxf(fabsf(rowsum[o]), fl[o]) + EPS_CELL);
  }
  int w = tid>>6, l = tid&63, lq = l>>4, lr = l&15;
  int wm = (w>>1)*16, wn = (w&1)*64;
  const bf16* Wbase = W + ((size_t)h*S_ + i0)*S_;
  const bf16* Vbase = vT + ((size_t)h*DH_ + d0)*S_;
  floatx4 acc[4];
  #pragma unroll
  for (int ni=0;ni<4;ni++) acc[ni] = (floatx4){0.f,0.f,0.f,0.f};
  short* Ws0 = smem;          short* Vs0 = smem + 4096;
  short* Ws1 = smem + 12288;  short* Vs1 = smem + 16384;
  int NT = (i0 >> 6) + 1;
  STAGE_ASYNC5(Ws0, Wbase, S_, 0);
  STAGE_ASYNC5(Vs0, Vbase, S_, 0);
  STAGE_ASYNC5(Vs0, Vbase, S_, 1);
  __syncthreads();
  for (int tt=0; tt<NT; ++tt){
    short* Ws  = (tt&1) ? Ws1 : Ws0;
    short* Vs  = (tt&1) ? Vs1 : Vs0;
    short* Wsn = (tt&1) ? Ws0 : Ws1;
    short* Vsn = (tt&1) ? Vs0 : Vs1;
    if (tt+1 < NT){
      int j0 = (tt+1)*64;
      STAGE_ASYNC5(Wsn, Wbase + j0, S_, 0);
      STAGE_ASYNC5(Vsn, Vbase + j0, S_, 0);
      STAGE_ASYNC5(Vsn, Vbase + j0, S_, 1);
    }
    #pragma unroll
    for (int ks=0; ks<2; ks++){
      bf16x8 af, bfr[4];
      af = *(const bf16x8*)&Ws[so_(wm+lr, ks*4+lq)];
      #pragma unroll
      for (int ni=0;ni<4;ni++) bfr[ni] = *(const bf16x8*)&Vs[so_(wn+ni*16+lr, ks*4+lq)];
      #pragma unroll
      for (int ni=0;ni<4;ni++)
        acc[ni] = __builtin_amdgcn_mfma_f32_16x16x32_bf16(af, bfr[ni], acc[ni], 0,0,0);
    }
    __syncthreads();
  }
  #pragma unroll
  for (int ni=0;ni<4;ni++){
    int dl = wn + ni*16 + lr;
    int ch = dl>>3, off = dl&7;
    #pragma unroll
    for (int r=0;r<4;r++){
      int rowl = wm + lq*4 + r;
      smem[rowl*128 + (((ch) ^ (rowl&15))<<3) + off] = (short)f2bu(acc[ni][r] * inv_s[rowl]);
    }
  }
  __syncthreads();
  #pragma unroll
  for (int i=0;i<2;i++){
    int slot = i*512 + tid;
    int r = slot >> 4, c8 = slot & 15;
    uint4 val = *(const uint4*)&smem[eo_(r, c8)];
    *(uint4*)(O + (size_t)(b*S_ + i0 + r)*INNER_ + n*DH_ + d0 + c8*8) = val;
  }
}

// ---------------- fused: w_down transpose (512 blocks) | headnorm+gate (16384) ----
__global__ __launch_bounds__(256) void headnorm_wdown(const bf16* __restrict__ h,
    const float* __restrict__ onw, const float* __restrict__ skip,
    const bf16* __restrict__ xca, bf16* __restrict__ up,
    const float* __restrict__ w_down, bf16* __restrict__ w_down_t){
  __shared__ float sa[256], sb[256];
  __shared__ float tl[64][65];
  int bid = blockIdx.x, tid = threadIdx.x;
  if (bid < 512){
    int n0 = (bid & 15)*64, k0 = (bid >> 4)*64;
    transpose_tile(w_down, w_down_t, INNER_, E_, n0, k0, tid, tl);
    return;
  }
  int id = bid - 512;
  int n = id & 3; int bs = id >> 2;
  size_t hbase = (size_t)bs*INNER_ + n*DH_;
  float v0 = b2f(h[hbase+tid]);
  float v1 = b2f(h[hbase+256+tid]);
  sa[tid]=v0+v1; sb[tid]=v0*v0+v1*v1;
  __syncthreads();
  for (int off=128; off>0; off>>=1){
    if (tid<off){ sa[tid]+=sa[tid+off]; sb[tid]+=sb[tid+off]; }
    __syncthreads();
  }
  float mean = sa[0]*(1.f/DH_);
  float var  = sb[0]*(1.f/DH_) - mean*mean;
  float rstd = rsqrtf(var + LN_EPS_);
  #pragma unroll
  for (int e=0;e<2;e++){
    int dl = e*256+tid; int c = n*DH_+dl;
    float hv = e ? v1 : v0;
    float hn = (hv-mean)*rstd*onw[c];
    float hs = hn + skip[c]*b2f(xca[(size_t)bs*INNER_+c]);
    size_t zoff = (size_t)bs*(2*INNER_) + INNER_ + c;
    float zv = b2f(up[zoff]);
    float sz = zv/(1.f+expf(-zv));
    up[zoff] = f2b(hs*sz);
  }
}

extern "C" void kernel_launch(void* const* d_in, const int* in_sizes, int n_in,
                              void* d_out, int out_size, void* d_ws, size_t ws_size,
                              hipStream_t stream) {
  const float* x      = (const float*)d_in[0];
  const float* w_in   = (const float*)d_in[1];
  const float* b_in   = (const float*)d_in[2];
  const float* ln1_w  = (const float*)d_in[3];
  const float* w_up   = (const float*)d_in[4];
  const float* b_up   = (const float*)d_in[5];
  const float* conv_w = (const float*)d_in[6];
  const float* conv_b = (const float*)d_in[7];
  const float* q_w    = (const float*)d_in[8];
  const float* q_b    = (const float*)d_in[9];
  const float* k_w    = (const float*)d_in[10];
  const float* k_b    = (const float*)d_in[11];
  const float* v_w    = (const float*)d_in[12];
  const float* v_b    = (const float*)d_in[13];
  const float* ig_w   = (const float*)d_in[14];
  const float* ig_b   = (const float*)d_in[15];
  const float* fg_w   = (const float*)d_in[16];
  const float* fg_b   = (const float*)d_in[17];
  const float* onw    = (const float*)d_in[18];
  const float* skip   = (const float*)d_in[19];
  const float* w_down = (const float*)d_in[20];
  const float* b_down = (const float*)d_in[21];
  const float* post_w = (const float*)d_in[22];

  char* p = (char*)d_ws;
  auto alloc = [&](size_t bytes)->void*{ void* r = p; p += (bytes + 255) & ~(size_t)255; return r; };
  bf16* h_in = (bf16*)alloc((size_t)T_*E_*2);        // 8 MB
  bf16* xn   = (bf16*)alloc((size_t)T_*E_*2);        // 8 MB (reused as y later)
  bf16* up   = (bf16*)alloc((size_t)T_*2*INNER_*2);  // 32 MB (x_m | z)
  bf16* xca  = (bf16*)alloc((size_t)T_*INNER_*2);    // 16 MB
  bf16* qb_  = (bf16*)alloc((size_t)T_*INNER_*2);
  bf16* kb_  = (bf16*)alloc((size_t)T_*INNER_*2);
  bf16* vb_  = (bf16*)alloc((size_t)T_*INNER_*2);    // v; later attention O
  bf16* hb_  = (bf16*)alloc((size_t)T_*INNER_*2);    // reused as vT (h,d,s)
  float* igbuf = (float*)alloc((size_t)B_*NH_*S_*4);
  float* fgbuf = (float*)alloc((size_t)B_*NH_*S_*4);
  float* abuf  = (float*)alloc((size_t)B_*NH_*S_*4);
  float* Mbuf  = (float*)alloc((size_t)B_*NH_*S_*4);
  float* flbuf = (float*)alloc((size_t)B_*NH_*S_*4);
  float* rsbuf = (float*)alloc((size_t)B_*NH_*S_*4);
  bf16* gwb  = (bf16*)alloc((size_t)3*INNER_*8*2);   // 96 KB packed gate weights
  bf16* Wbuf = (bf16*)alloc((size_t)B_*NH_*S_*S_*2); // 67 MB decay-weighted scores
  bf16* ybuf = xn;
  bf16* vTb  = hb_;
  bf16* obuf = vb_;
  bf16* xbf    = Wbuf;                               // 4 MB, dead after GEMM1
  bf16* w_in_t = Wbuf + (size_t)T_*IN_;              // 1 MB, dead after GEMM1
  bf16* w_up_t = w_in_t + (size_t)E_*IN_;            // 8 MB, dead after GEMM2
  bf16* w_down_t = Wbuf;                             // written AFTER pv frees Wbuf

  // 0. fused prep: convert x, transpose w_in/w_up, pack gate weights
  prep_fused<<<2200, 256, 0, stream>>>(x, w_in, w_up, ig_w, fg_w,
      xbf, w_in_t, w_up_t, gwb);
  // 1. h_in = x @ w_in + b_in   (64x128 tiles: 512 blocks)
  mfma_gemm64<<<(T_/64)*(E_/128), 256, 0, stream>>>(xbf, w_in_t, b_in, h_in, IN_, IN_, E_, E_/128);
  // 2. xn = LN(h_in)*ln1_w
  ln_rows<bf16><<<T_, 256, 0, stream>>>(h_in, nullptr, ln1_w, xn);
  // 3. up = xn @ w_up + b_up   (128x128: 1024 blocks)
  mfma_gemm<<<(T_/128)*((2*INNER_)/128), 256, 0, stream>>>(xn, w_up_t, b_up, up, E_, E_, 2*INNER_, (2*INNER_)/128);
  // 4+5. fused conv+SiLU and q/k/v projections
  conv_headwise<<<T_/CTB_, 256, 0, stream>>>(up, conv_w, conv_b,
      q_w, q_b, k_w, k_b, v_w, v_b, xca, qb_, kb_, vb_);
  // 6+8. fused gates GEMV + v->vT transpose
  gates_transv<<<512 + 2048, 256, 0, stream>>>(qb_, kb_, vb_, gwb, ig_b, fg_b,
      igbuf, fgbuf, vTb);
  // 7. scans: a, M, floor; zero rowsums
  scan8<<<B_*NH_, 256, 0, stream>>>(igbuf, fgbuf, abuf, Mbuf, flbuf, rsbuf);
  // 9. W = QK^T * scale * decay (64x128 lower-triangle tiles, 8 waves/block), rowsums
  qk_decay_kernel<<<8*272, 512, 0, stream>>>(qb_, kb_, abuf, Mbuf, rsbuf, Wbuf);
  // 10. O = (W*inv) @ V -> obuf (8 waves/block)
  pv_kernel<<<8*128, 512, 0, stream>>>(Wbuf, vTb, rsbuf, flbuf, obuf);
  // 11. fused: w_down transpose (Wbuf now dead) + headnorm/skip/gate into z
  headnorm_wdown<<<512 + T_*NH_, 256, 0, stream>>>(obuf, onw, skip, xca, up,
      w_down, w_down_t);
  // 12. y = h_gated @ w_down + b_down   (64x128 tiles: 512 blocks)
  mfma_gemm64<<<(T_/64)*(E_/128), 256, 0, stream>>>(up + INNER_, w_down_t, b_down, ybuf, INNER_, 2*INNER_, E_, E_/128);
  // 13. out = LN(h_in + y)*post_w
  ln_rows<float><<<T_, 256, 0, stream>>>(h_in, ybuf, post_w, (float*)d_out);
}

// Round 8
// 353.630 us; speedup vs baseline: 1.1365x; 1.0423x over previous
//
#include <hip/hip_runtime.h>
#include <hip/hip_bf16.h>

typedef __hip_bfloat16 bf16;
typedef float floatx4 __attribute__((ext_vector_type(4)));
typedef short bf16x8 __attribute__((ext_vector_type(8)));

#define B_      2
#define S_      2048
#define IN_     512
#define E_      1024
#define INNER_  2048
#define NH_     4
#define DH_     512
#define T_      (B_*S_)      // 4096 tokens
#define EPS_CELL 1e-6f
#define LN_EPS_  1e-5f
#define LS      72           // padded LDS row stride (shorts) for non-async kernels
#define CTB_    4            // tokens per block in conv_headwise

__device__ inline float b2f(bf16 x){ return __bfloat162float(x); }
__device__ inline bf16  f2b(float x){ return __float2bfloat16(x); }
__device__ inline float u2f(unsigned int u){ union{unsigned int i; float f;} v; v.i = u; return v.f; }
__device__ inline unsigned short f2bu(float x){ bf16 t = __float2bfloat16(x); unsigned short r; __builtin_memcpy(&r,&t,2); return r; }
__device__ inline void unpack8(uint4 u, float* f){
  f[0]=u2f(u.x<<16); f[1]=u2f(u.x&0xffff0000u);
  f[2]=u2f(u.y<<16); f[3]=u2f(u.y&0xffff0000u);
  f[4]=u2f(u.z<<16); f[5]=u2f(u.z&0xffff0000u);
  f[6]=u2f(u.w<<16); f[7]=u2f(u.w&0xffff0000u);
}
__device__ inline uint4 pack8(const float* f){
  uint4 u;
  u.x = (unsigned)f2bu(f[0]) | ((unsigned)f2bu(f[1])<<16);
  u.y = (unsigned)f2bu(f[2]) | ((unsigned)f2bu(f[3])<<16);
  u.z = (unsigned)f2bu(f[4]) | ((unsigned)f2bu(f[5])<<16);
  u.w = (unsigned)f2bu(f[6]) | ((unsigned)f2bu(f[7])<<16);
  return u;
}
__device__ inline void stv(bf16* p, float v){ *p = f2b(v); }
__device__ inline void stv(float* p, float v){ *p = v; }

// ---- async 16B global->LDS copy (wave-uniform base + lane*16 pattern) ----
typedef __attribute__((address_space(3))) unsigned int lds_u32_t;
typedef __attribute__((address_space(1))) const unsigned int glb_u32_t;
__device__ __forceinline__ void cp_async16(const bf16* g, short* l){
  __builtin_amdgcn_global_load_lds((glb_u32_t*)(const void*)g,
                                   (lds_u32_t*)(void*)l, 16, 0, 0);
}
// swizzled LDS offset (shorts) for Nx64 tile: row-dense, chunk XOR row&7
__device__ __forceinline__ int so_(int row, int c8){ return row*64 + (((c8) ^ (row&7))<<3); }
// epilogue repack offset for Nx128-short tile: chunk XOR row&15
__device__ __forceinline__ int eo_(int row, int ch){ return row*128 + (((ch) ^ (row&15))<<3); }

// stage rows of a tile with 256 threads (row stride `stride` in global)
#define STAGE_ASYNC(dst, srcbase, stride, kk) \
  { int slot_ = (kk)*256 + tid; int r_ = slot_>>3; int c8_ = (slot_&7) ^ (r_&7); \
    cp_async16((srcbase) + (size_t)r_*(stride) + c8_*8, &dst[slot_*8]); }

// stage with 512 threads
#define STAGE_ASYNC5(dst, srcbase, stride, kk) \
  { int slot_ = (kk)*512 + tid; int r_ = slot_>>3; int c8_ = (slot_&7) ^ (r_&7); \
    cp_async16((srcbase) + (size_t)r_*(stride) + c8_*8, &dst[slot_*8]); }

// counted waits + raw barrier for the GEMM kernels only (no pre-loop vmem ops
// there, so the per-wave vmcnt bookkeeping is exact).
#define VMWAIT8() asm volatile("s_waitcnt vmcnt(8)" ::: "memory")
#define VMWAIT6() asm volatile("s_waitcnt vmcnt(6)" ::: "memory")
#define VMWAIT0() asm volatile("s_waitcnt vmcnt(0)" ::: "memory")
#define RAWBAR()  do { asm volatile("" ::: "memory"); __builtin_amdgcn_s_barrier(); asm volatile("" ::: "memory"); } while(0)

// ---------------- W[K,N] fp32 -> Wt[N,K] bf16 (64x64 LDS tile), device body ----
__device__ inline void transpose_tile(const float* W, bf16* Wt, int K, int N,
    int n0, int k0, int tid, float (*tl)[65]){
  #pragma unroll
  for (int i=0;i<4;i++){
    int idx = tid + i*256; int r = idx>>4, c4 = idx&15;
    float4 v = *(const float4*)(W + (size_t)(k0+r)*N + n0 + c4*4);
    tl[r][c4*4+0]=v.x; tl[r][c4*4+1]=v.y; tl[r][c4*4+2]=v.z; tl[r][c4*4+3]=v.w;
  }
  __syncthreads();
  #pragma unroll
  for (int i=0;i<4;i++){
    int idx = tid + i*256; int rn = idx>>4, c4 = idx&15;
    ushort4 o;
    o.x=f2bu(tl[c4*4+0][rn]); o.y=f2bu(tl[c4*4+1][rn]);
    o.z=f2bu(tl[c4*4+2][rn]); o.w=f2bu(tl[c4*4+3][rn]);
    *(ushort4*)(Wt + (size_t)(n0+rn)*K + k0 + c4*4) = o;
  }
}

// ---------------- fused prep: convert x | transpose w_in | transpose w_up | pack gates ----
__global__ __launch_bounds__(256) void prep_fused(const float* __restrict__ x,
    const float* __restrict__ w_in, const float* __restrict__ w_up,
    const float* __restrict__ igw, const float* __restrict__ fgw,
    bf16* __restrict__ xbf, bf16* __restrict__ w_in_t, bf16* __restrict__ w_up_t,
    bf16* __restrict__ gwb){
  __shared__ float tl[64][65];
  int bid = blockIdx.x, tid = threadIdx.x;
  if (bid < 1024){
    int i = bid*256 + tid;
    const float4* p = (const float4*)(x) + i*2;
    float4 a = p[0], b = p[1];
    ushort4 o0, o1;
    o0.x=f2bu(a.x); o0.y=f2bu(a.y); o0.z=f2bu(a.z); o0.w=f2bu(a.w);
    o1.x=f2bu(b.x); o1.y=f2bu(b.y); o1.z=f2bu(b.z); o1.w=f2bu(b.w);
    ushort4* q = (ushort4*)(xbf) + i*2;
    q[0]=o0; q[1]=o1;
  } else if (bid < 1152){
    int id = bid - 1024;
    int n0 = (id & 15)*64, k0 = (id >> 4)*64;
    transpose_tile(w_in, w_in_t, IN_, E_, n0, k0, tid, tl);
  } else if (bid < 2176){
    int id = bid - 1152;
    int n0 = (id & 63)*64, k0 = (id >> 6)*64;
    transpose_tile(w_up, w_up_t, E_, 2*INNER_, n0, k0, tid, tl);
  } else {
    int idx = (bid - 2176)*256 + tid;
    if (idx < 3*INNER_){
      int g = idx >> 9;
      int e = (idx >> 6) & 7;
      int l = idx & 63;
      int r = g*512 + l*8 + e;
      float4 a = *(const float4*)(igw + (size_t)r*4);
      float4 b = *(const float4*)(fgw + (size_t)r*4);
      ushort4 o0, o1;
      o0.x=f2bu(a.x); o0.y=f2bu(a.y); o0.z=f2bu(a.z); o0.w=f2bu(a.w);
      o1.x=f2bu(b.x); o1.y=f2bu(b.y); o1.z=f2bu(b.z); o1.w=f2bu(b.w);
      *(ushort4*)(gwb + (size_t)idx*8)     = o0;
      *(ushort4*)(gwb + (size_t)idx*8 + 4) = o1;
    }
  }
}

// ---------------- MFMA GEMM 128x128: C = A @ Bt^T + bias ----------------
// Depth-2 counted-vmcnt pipeline: 8 loads/tile/wave; vmcnt(8) keeps exactly
// tile t+1 in flight; every wave waits its own count before the raw barrier,
// so after the barrier all waves' tile-t loads have landed. No other vmem ops
// precede/interleave the loop (bias load is after), so counts are exact.
__global__ __launch_bounds__(256) void mfma_gemm(const bf16* __restrict__ A,
    const bf16* __restrict__ Bt, const float* __restrict__ bias, bf16* __restrict__ C,
    int Kd, int lda, int ldc, int NN){
  int bid = blockIdx.x;
  int MM = gridDim.x / NN;
  int mPerX = MM >> 3;
  int xcd = bid & 7, seq = bid >> 3;
  int nb = seq % NN, mb = xcd*mPerX + seq / NN;
  int n0 = nb*128, m0 = mb*128;
  __shared__ __align__(16) short smem[32768];
  int tid = threadIdx.x;
  int w = tid>>6, l = tid&63, lq = l>>4, lr = l&15;
  int wm = (w>>1)*64, wn = (w&1)*64;
  const bf16* Abase = A + (size_t)m0*lda;
  const bf16* Bbase = Bt + (size_t)n0*Kd;
  floatx4 acc[4][4];
  #pragma unroll
  for (int mi=0;mi<4;mi++){
    #pragma unroll
    for (int ni=0;ni<4;ni++) acc[mi][ni] = (floatx4){0.f,0.f,0.f,0.f};
  }
  short* As0 = smem;          short* Bs0 = smem + 8192;
  short* As1 = smem + 16384;  short* Bs1 = smem + 24576;
  int NT = Kd >> 6;
  // prologue: stage tiles 0 and 1
  #pragma unroll
  for (int kk=0;kk<4;kk++){
    STAGE_ASYNC(As0, Abase, lda, kk);
    STAGE_ASYNC(Bs0, Bbase, Kd, kk);
  }
  #pragma unroll
  for (int kk=0;kk<4;kk++){
    STAGE_ASYNC(As1, Abase + 64, lda, kk);
    STAGE_ASYNC(Bs1, Bbase + 64, Kd, kk);
  }
  for (int t=0; t<NT; ++t){
    if (t < NT-1) { VMWAIT8(); } else { VMWAIT0(); }
    RAWBAR();
    short* As = (t&1) ? As1 : As0;
    short* Bs = (t&1) ? Bs1 : Bs0;
    #pragma unroll
    for (int ks=0; ks<2; ks++){
      bf16x8 af[4], bfr[4];
      #pragma unroll
      for (int mi=0;mi<4;mi++) af[mi] = *(const bf16x8*)&As[so_(wm+mi*16+lr, ks*4+lq)];
      #pragma unroll
      for (int ni=0;ni<4;ni++) bfr[ni] = *(const bf16x8*)&Bs[so_(wn+ni*16+lr, ks*4+lq)];
      #pragma unroll
      for (int mi=0;mi<4;mi++){
        #pragma unroll
        for (int ni=0;ni<4;ni++)
          acc[mi][ni] = __builtin_amdgcn_mfma_f32_16x16x32_bf16(af[mi], bfr[ni], acc[mi][ni], 0,0,0);
      }
    }
    RAWBAR();
    if (t+2 < NT){
      int k0 = (t+2)*64;
      #pragma unroll
      for (int kk=0;kk<4;kk++){
        STAGE_ASYNC(As, Abase + k0, lda, kk);
        STAGE_ASYNC(Bs, Bbase + k0, Kd, kk);
      }
    }
  }
  float bb[4];
  #pragma unroll
  for (int ni=0;ni<4;ni++) bb[ni] = bias[n0 + wn + ni*16 + lr];
  __syncthreads();   // staging LDS dead -> reuse for C repack
  #pragma unroll
  for (int mi=0;mi<4;mi++){
    #pragma unroll
    for (int ni=0;ni<4;ni++){
      int coll = wn + ni*16 + lr;
      int ch = coll>>3, off = coll&7;
      #pragma unroll
      for (int r=0;r<4;r++){
        int rowl = wm + mi*16 + lq*4 + r;
        smem[rowl*128 + (((ch) ^ (rowl&15))<<3) + off] = (short)f2bu(acc[mi][ni][r] + bb[ni]);
      }
    }
  }
  __syncthreads();
  #pragma unroll
  for (int i=0;i<8;i++){
    int slot = i*256 + tid;
    int r = slot >> 4, c8 = slot & 15;
    uint4 val = *(const uint4*)&smem[eo_(r, c8)];
    *(uint4*)(C + (size_t)(m0+r)*ldc + n0 + c8*8) = val;
  }
}

// ---------------- MFMA GEMM 64x128 tile (for N=1024 GEMMs: 512 blocks = 2/CU) ----
// Same depth-2 counted-vmcnt pipeline; 6 loads/tile -> vmcnt(6).
__global__ __launch_bounds__(256) void mfma_gemm64(const bf16* __restrict__ A,
    const bf16* __restrict__ Bt, const float* __restrict__ bias, bf16* __restrict__ C,
    int Kd, int lda, int ldc, int NN){
  int bid = blockIdx.x;
  int MM = gridDim.x / NN;
  int mPerX = MM >> 3;
  int xcd = bid & 7, seq = bid >> 3;
  int nb = seq % NN, mb = xcd*mPerX + seq / NN;
  int n0 = nb*128, m0 = mb*64;
  __shared__ __align__(16) short smem[24576];
  int tid = threadIdx.x;
  int w = tid>>6, l = tid&63, lq = l>>4, lr = l&15;
  int wm = (w>>1)*32, wn = (w&1)*64;
  const bf16* Abase = A + (size_t)m0*lda;
  const bf16* Bbase = Bt + (size_t)n0*Kd;
  floatx4 acc[2][4];
  #pragma unroll
  for (int mi=0;mi<2;mi++){
    #pragma unroll
    for (int ni=0;ni<4;ni++) acc[mi][ni] = (floatx4){0.f,0.f,0.f,0.f};
  }
  short* As0 = smem;          short* Bs0 = smem + 4096;
  short* As1 = smem + 12288;  short* Bs1 = smem + 16384;
  int NT = Kd >> 6;
  // prologue: stage tiles 0 and 1
  STAGE_ASYNC(As0, Abase, lda, 0);
  STAGE_ASYNC(As0, Abase, lda, 1);
  #pragma unroll
  for (int kk=0;kk<4;kk++){ STAGE_ASYNC(Bs0, Bbase, Kd, kk); }
  STAGE_ASYNC(As1, Abase + 64, lda, 0);
  STAGE_ASYNC(As1, Abase + 64, lda, 1);
  #pragma unroll
  for (int kk=0;kk<4;kk++){ STAGE_ASYNC(Bs1, Bbase + 64, Kd, kk); }
  for (int t=0; t<NT; ++t){
    if (t < NT-1) { VMWAIT6(); } else { VMWAIT0(); }
    RAWBAR();
    short* As = (t&1) ? As1 : As0;
    short* Bs = (t&1) ? Bs1 : Bs0;
    #pragma unroll
    for (int ks=0; ks<2; ks++){
      bf16x8 af[2], bfr[4];
      #pragma unroll
      for (int mi=0;mi<2;mi++) af[mi] = *(const bf16x8*)&As[so_(wm+mi*16+lr, ks*4+lq)];
      #pragma unroll
      for (int ni=0;ni<4;ni++) bfr[ni] = *(const bf16x8*)&Bs[so_(wn+ni*16+lr, ks*4+lq)];
      #pragma unroll
      for (int mi=0;mi<2;mi++){
        #pragma unroll
        for (int ni=0;ni<4;ni++)
          acc[mi][ni] = __builtin_amdgcn_mfma_f32_16x16x32_bf16(af[mi], bfr[ni], acc[mi][ni], 0,0,0);
      }
    }
    RAWBAR();
    if (t+2 < NT){
      int k0 = (t+2)*64;
      STAGE_ASYNC(As, Abase + k0, lda, 0);
      STAGE_ASYNC(As, Abase + k0, lda, 1);
      #pragma unroll
      for (int kk=0;kk<4;kk++){ STAGE_ASYNC(Bs, Bbase + k0, Kd, kk); }
    }
  }
  float bb[4];
  #pragma unroll
  for (int ni=0;ni<4;ni++) bb[ni] = bias[n0 + wn + ni*16 + lr];
  __syncthreads();   // staging LDS dead -> reuse for C repack
  #pragma unroll
  for (int mi=0;mi<2;mi++){
    #pragma unroll
    for (int ni=0;ni<4;ni++){
      int coll = wn + ni*16 + lr;
      int ch = coll>>3, off = coll&7;
      #pragma unroll
      for (int r=0;r<4;r++){
        int rowl = wm + mi*16 + lq*4 + r;
        smem[rowl*128 + (((ch) ^ (rowl&15))<<3) + off] = (short)f2bu(acc[mi][ni][r] + bb[ni]);
      }
    }
  }
  __syncthreads();
  #pragma unroll
  for (int i=0;i<4;i++){
    int slot = i*256 + tid;
    int r = slot >> 4, c8 = slot & 15;
    uint4 val = *(const uint4*)&smem[eo_(r, c8)];
    *(uint4*)(C + (size_t)(m0+r)*ldc + n0 + c8*8) = val;
  }
}

// ---------------- layernorm over rows of length E_ (opt. fused add) ----------------
template<typename OutT>
__global__ __launch_bounds__(256) void ln_rows(const bf16* __restrict__ X,
    const bf16* __restrict__ Xadd, const float* __restrict__ w, OutT* __restrict__ Y){
  int row = blockIdx.x, tid = threadIdx.x;
  size_t base = (size_t)row*E_;
  float vals[4], s=0.f, s2=0.f;
  #pragma unroll
  for (int e=0;e<4;e++){
    int c = e*256+tid;
    float v = b2f(X[base+c]);
    if (Xadd) v += b2f(Xadd[base+c]);
    vals[e]=v; s+=v; s2+=v*v;
  }
  __shared__ float sa[256], sb[256];
  sa[tid]=s; sb[tid]=s2; __syncthreads();
  for (int off=128; off>0; off>>=1){
    if (tid<off){ sa[tid]+=sa[tid+off]; sb[tid]+=sb[tid+off]; }
    __syncthreads();
  }
  float mean = sa[0]*(1.f/E_);
  float var  = sb[0]*(1.f/E_) - mean*mean;
  float rstd = rsqrtf(var + LN_EPS_);
  #pragma unroll
  for (int e=0;e<4;e++){
    int c = e*256+tid;
    stv(&Y[base+c], (vals[e]-mean)*rstd*w[c]);
  }
}

// ---------------- fused causal conv(K=4)+SiLU and block-diagonal q/k/v ----------------
__global__ __launch_bounds__(256) void conv_headwise(const bf16* __restrict__ up,
    const float* __restrict__ cw, const float* __restrict__ cb,
    const float* __restrict__ qw, const float* __restrict__ qb,
    const float* __restrict__ kw, const float* __restrict__ kb,
    const float* __restrict__ vw, const float* __restrict__ vb,
    bf16* __restrict__ xca, bf16* __restrict__ q, bf16* __restrict__ k,
    bf16* __restrict__ v){
  int t0 = blockIdx.x*CTB_;
  int s0 = t0 & (S_-1);
  int c0 = threadIdx.x*8;
  int hw0 = c0 >> 2;

  float row[7][8];
  #pragma unroll
  for (int j=0;j<7;j++){
    if (s0-3+j >= 0){
      uint4 rv = *(const uint4*)(up + (size_t)(t0-3+j)*(2*INNER_) + c0);
      unpack8(rv, row[j]);
    } else {
      #pragma unroll
      for (int e=0;e<8;e++) row[j][e]=0.f;
    }
  }

  float xc[CTB_][8];
  {
    float cwv[8][4], cbv[8];
    #pragma unroll
    for (int e=0;e<8;e++){
      float4 w4 = *(const float4*)(cw + (size_t)(c0+e)*4);
      cwv[e][0]=w4.x; cwv[e][1]=w4.y; cwv[e][2]=w4.z; cwv[e][3]=w4.w;
    }
    float4 b0 = *(const float4*)(cb+c0), b1 = *(const float4*)(cb+c0+4);
    cbv[0]=b0.x; cbv[1]=b0.y; cbv[2]=b0.z; cbv[3]=b0.w;
    cbv[4]=b1.x; cbv[5]=b1.y; cbv[6]=b1.z; cbv[7]=b1.w;
    #pragma unroll
    for (int i=0;i<CTB_;i++){
      #pragma unroll
      for (int e=0;e<8;e++){
        float a = cbv[e];
        #pragma unroll
        for (int t=0;t<4;t++) a += row[i+t][e]*cwv[e][t];
        xc[i][e] = a/(1.f+expf(-a));
      }
      *(uint4*)(xca + (size_t)(t0+i)*INNER_ + c0) = pack8(xc[i]);
    }
  }

  {
    float wv_[32], bv[8];
    #pragma unroll
    for (int g=0;g<2;g++){
      #pragma unroll
      for (int r4=0;r4<4;r4++){
        float4 w4 = *(const float4*)(vw + (size_t)(hw0+g)*16 + r4*4);
        wv_[g*16+r4*4+0]=w4.x; wv_[g*16+r4*4+1]=w4.y;
        wv_[g*16+r4*4+2]=w4.z; wv_[g*16+r4*4+3]=w4.w;
      }
    }
    float4 b0 = *(const float4*)(vb+c0), b1 = *(const float4*)(vb+c0+4);
    bv[0]=b0.x; bv[1]=b0.y; bv[2]=b0.z; bv[3]=b0.w;
    bv[4]=b1.x; bv[5]=b1.y; bv[6]=b1.z; bv[7]=b1.w;
    #pragma unroll
    for (int i=0;i<CTB_;i++){
      float ov[8];
      #pragma unroll
      for (int g=0;g<2;g++){
        #pragma unroll
        for (int o=0;o<4;o++){
          float a = bv[g*4+o];
          #pragma unroll
          for (int d=0;d<4;d++) a += row[i+3][g*4+d]*wv_[g*16+o*4+d];
          ov[g*4+o]=a;
        }
      }
      *(uint4*)(v + (size_t)(t0+i)*INNER_ + c0) = pack8(ov);
    }
  }

  {
    float wv_[32], bv[8];
    #pragma unroll
    for (int g=0;g<2;g++){
      #pragma unroll
      for (int r4=0;r4<4;r4++){
        float4 w4 = *(const float4*)(qw + (size_t)(hw0+g)*16 + r4*4);
        wv_[g*16+r4*4+0]=w4.x; wv_[g*16+r4*4+1]=w4.y;
        wv_[g*16+r4*4+2]=w4.z; wv_[g*16+r4*4+3]=w4.w;
      }
    }
    float4 b0 = *(const float4*)(qb+c0), b1 = *(const float4*)(qb+c0+4);
    bv[0]=b0.x; bv[1]=b0.y; bv[2]=b0.z; bv[3]=b0.w;
    bv[4]=b1.x; bv[5]=b1.y; bv[6]=b1.z; bv[7]=b1.w;
    #pragma unroll
    for (int i=0;i<CTB_;i++){
      float ov[8];
      #pragma unroll
      for (int g=0;g<2;g++){
        #pragma unroll
        for (int o=0;o<4;o++){
          float a = bv[g*4+o];
          #pragma unroll
          for (int d=0;d<4;d++) a += xc[i][g*4+d]*wv_[g*16+o*4+d];
          ov[g*4+o]=a;
        }
      }
      *(uint4*)(q + (size_t)(t0+i)*INNER_ + c0) = pack8(ov);
    }
  }

  {
    float wv_[32], bv[8];
    #pragma unroll
    for (int g=0;g<2;g++){
      #pragma unroll
      for (int r4=0;r4<4;r4++){
        float4 w4 = *(const float4*)(kw + (size_t)(hw0+g)*16 + r4*4);
        wv_[g*16+r4*4+0]=w4.x; wv_[g*16+r4*4+1]=w4.y;
        wv_[g*16+r4*4+2]=w4.z; wv_[g*16+r4*4+3]=w4.w;
      }
    }
    float4 b0 = *(const float4*)(kb+c0), b1 = *(const float4*)(kb+c0+4);
    bv[0]=b0.x; bv[1]=b0.y; bv[2]=b0.z; bv[3]=b0.w;
    bv[4]=b1.x; bv[5]=b1.y; bv[6]=b1.z; bv[7]=b1.w;
    #pragma unroll
    for (int i=0;i<CTB_;i++){
      float ov[8];
      #pragma unroll
      for (int g=0;g<2;g++){
        #pragma unroll
        for (int o=0;o<4;o++){
          float a = bv[g*4+o];
          #pragma unroll
          for (int d=0;d<4;d++) a += xc[i][g*4+d]*wv_[g*16+o*4+d];
          ov[g*4+o]=a;
        }
      }
      *(uint4*)(k + (size_t)(t0+i)*INNER_ + c0) = pack8(ov);
    }
  }
}

// ---------------- fused: gates GEMV (512 blocks) | v->vT transpose (2048 blocks) ----
__global__ __launch_bounds__(256) void gates_transv(const bf16* __restrict__ q,
    const bf16* __restrict__ k, const bf16* __restrict__ v,
    const bf16* __restrict__ gwb, const float* __restrict__ igb,
    const float* __restrict__ fgb, float* __restrict__ igo, float* __restrict__ fgo,
    bf16* __restrict__ vT){
  __shared__ float red[4*32];
  __shared__ short tl[64*LS];
  int bid = blockIdx.x, tid = threadIdx.x;
  if (bid < 512){
    int w = tid >> 6, l = tid & 63;
    int quad = w >> 1, kh = w & 1;
    int tok0 = bid*8 + quad*4;
    float acc[4][8];
    #pragma unroll
    for (int t=0;t<4;t++){
      #pragma unroll
      for (int n=0;n<8;n++) acc[t][n]=0.f;
    }
    #pragma unroll 2
    for (int it=0; it<6; ++it){
      int src = it >> 1, j = it & 1;
      const bf16* sp = (src==0) ? q : ((src==1) ? k : v);
      int pos = kh*1024 + j*512 + l*8;
      int g = src*4 + kh*2 + j;
      uint4 dv[4];
      #pragma unroll
      for (int t=0;t<4;t++)
        dv[t] = *(const uint4*)(sp + (size_t)(tok0+t)*INNER_ + pos);
      float d[4][8];
      #pragma unroll
      for (int t=0;t<4;t++) unpack8(dv[t], d[t]);
      const bf16* wb = gwb + (size_t)g*512*8;
      #pragma unroll
      for (int e=0;e<8;e++){
        uint4 wv = *(const uint4*)(wb + (size_t)(e*64 + l)*8);
        float w8[8]; unpack8(wv, w8);
        #pragma unroll
        for (int t=0;t<4;t++){
          #pragma unroll
          for (int n=0;n<8;n++) acc[t][n] += d[t][e]*w8[n];
        }
      }
    }
    #pragma unroll
    for (int off=1; off<64; off<<=1){
      #pragma unroll
      for (int t=0;t<4;t++){
        #pragma unroll
        for (int n=0;n<8;n++) acc[t][n] += __shfl_xor(acc[t][n], off);
      }
    }
    if (l == 0){
      #pragma unroll
      for (int t=0;t<4;t++){
        #pragma unroll
        for (int n=0;n<8;n++) red[w*32 + t*8 + n] = acc[t][n];
      }
    }
    __syncthreads();
    if (tid < 64){
      int qd = tid >> 5, tn = tid & 31;
      int t = tn >> 3, n = tn & 7;
      float val = red[(qd*2)*32 + tn] + red[(qd*2+1)*32 + tn];
      int tok = bid*8 + qd*4 + t;
      int b = tok >> 11, s = tok & (S_-1);
      if (n < 4) igo[((size_t)(b*NH_+n))*S_ + s] = val + igb[n];
      else       fgo[((size_t)(b*NH_+(n-4)))*S_ + s] = val + fgb[n-4];
    }
  } else {
    int id = bid - 512;
    int sb = id & 31, db = (id >> 5) & 7, h = id >> 8;
    int b = h >> 2, n = h & 3;
    int s0 = sb*64, d0 = db*64;
    #pragma unroll
    for (int i=0;i<2;i++){
      int vv = tid + i*256; int r = vv>>3, c8 = vv&7;
      uint4 x = *(const uint4*)(v + (size_t)(b*S_+s0+r)*INNER_ + n*DH_ + d0 + c8*8);
      *(uint4*)&tl[r*LS + c8*8] = x;
    }
    __syncthreads();
    #pragma unroll
    for (int i=0;i<2;i++){
      int vv = tid + i*256; int r = vv>>3, c8 = vv&7;
      unsigned short tmp[8];
      #pragma unroll
      for (int e=0;e<8;e++) tmp[e] = (unsigned short)tl[(c8*8+e)*LS + r];
      uint4 o; __builtin_memcpy(&o, tmp, 16);
      *(uint4*)(vT + ((size_t)h*DH_ + d0 + r)*S_ + s0 + c8*8) = o;
    }
  }
}

// ---------------- per-head scan: F=cumsum(logsigmoid(fg)); a=ig-F; M=prefmax(a) ----
__global__ __launch_bounds__(256) void scan8(const float* __restrict__ igp,
    const float* __restrict__ fgp, float* __restrict__ ap,
    float* __restrict__ Mp, float* __restrict__ flp, float* __restrict__ rowsum){
  int h = blockIdx.x, tid = threadIdx.x;
  const float* fg = fgp + (size_t)h*S_;
  const float* ig = igp + (size_t)h*S_;
  int base = tid*8;
  float loc[8], run = 0.f;
  #pragma unroll
  for (int e=0;e<8;e++){
    float x = fg[base+e];
    float ls = fminf(x,0.f) - log1pf(expf(-fabsf(x)));
    run += ls; loc[e] = run;
  }
  __shared__ float sd[256];
  sd[tid]=run; __syncthreads();
  if (tid==0){ float r=0.f; for(int t=0;t<256;t++){ float t0=sd[t]; sd[t]=r; r+=t0; } }
  __syncthreads();
  float off = sd[tid];
  float lm[8], rm = -3e38f;
  #pragma unroll
  for (int e=0;e<8;e++){
    float F = loc[e]+off; loc[e]=F;
    float aj = ig[base+e]-F;
    ap[(size_t)h*S_+base+e]=aj;
    rm = fmaxf(rm, aj); lm[e]=rm;
  }
  __syncthreads();
  sd[tid]=rm; __syncthreads();
  if (tid==0){ float r=-3e38f; for(int t=0;t<256;t++){ float t0=sd[t]; sd[t]=r; r=fmaxf(r,t0); } }
  __syncthreads();
  float offm = sd[tid];
  #pragma unroll
  for (int e=0;e<8;e++){
    float M = fmaxf(lm[e], offm);
    Mp[(size_t)h*S_+base+e]=M;
    flp[(size_t)h*S_+base+e]=expf(-loc[e]-M);
    rowsum[(size_t)h*S_+base+e]=0.f;
  }
}

// ---------------- W = (Q K^T)*scale*exp(a_j - M_i), causal; + rowsums ----------------
// 64x128 i x j tiles, lower triangle; grid 8*272, h = bid&7 (XCD-pinned).
// 512 threads = 8 waves (4 i-groups x 2 j-groups); 2-phase double-buffer.
__global__ __launch_bounds__(512) void qk_decay_kernel(const bf16* __restrict__ qg,
    const bf16* __restrict__ kg, const float* __restrict__ ap,
    const float* __restrict__ Mp, float* __restrict__ rowsum, bf16* __restrict__ W){
  int h = blockIdx.x & 7;
  int t = 271 - (blockIdx.x >> 3);
  int p = (int)((sqrtf(4.f*t+1.f)-1.f)*0.5f);
  while ((p+1)*(p+2) <= t) p++;
  while (p*(p+1) > t) p--;
  int r0 = t - p*(p+1);
  int nj = p + 1;
  int it = 2*p + (r0 >= nj ? 1 : 0);
  int tj = r0 >= nj ? r0 - nj : r0;
  int b = h >> 2, n = h & 3;
  int i0 = it*64, j0 = tj*128;
  __shared__ __align__(16) short smem[2*12288];
  __shared__ float a_s[128], m_s[64];
  int tid = threadIdx.x;
  if (tid < 128) a_s[tid] = ap[(size_t)h*S_ + j0 + tid];
  if (tid < 64)  m_s[tid] = Mp[(size_t)h*S_ + i0 + tid];
  int w = tid>>6, l = tid&63, lq = l>>4, lr = l&15;
  int wm = (w>>1)*16, wn = (w&1)*64;
  const bf16* Qbase = qg + (size_t)(b*S_+i0)*INNER_ + n*DH_;
  const bf16* Kbase = kg + (size_t)(b*S_+j0)*INNER_ + n*DH_;
  floatx4 acc[4];
  #pragma unroll
  for (int ni=0;ni<4;ni++) acc[ni] = (floatx4){0.f,0.f,0.f,0.f};
  short* Qs0 = smem;          short* Ks0 = smem + 4096;
  short* Qs1 = smem + 12288;  short* Ks1 = smem + 16384;
  STAGE_ASYNC5(Qs0, Qbase, INNER_, 0);
  STAGE_ASYNC5(Ks0, Kbase, INNER_, 0);
  STAGE_ASYNC5(Ks0, Kbase, INNER_, 1);
  __syncthreads();
  const int NT = DH_/64;   // 8
  for (int tt=0; tt<NT; ++tt){
    short* Qs  = (tt&1) ? Qs1 : Qs0;
    short* Ks  = (tt&1) ? Ks1 : Ks0;
    short* Qsn = (tt&1) ? Qs0 : Qs1;
    short* Ksn = (tt&1) ? Ks0 : Ks1;
    if (tt+1 < NT){
      int d0 = (tt+1)*64;
      STAGE_ASYNC5(Qsn, Qbase + d0, INNER_, 0);
      STAGE_ASYNC5(Ksn, Kbase + d0, INNER_, 0);
      STAGE_ASYNC5(Ksn, Kbase + d0, INNER_, 1);
    }
    #pragma unroll
    for (int ks=0; ks<2; ks++){
      bf16x8 af, bfr[4];
      af = *(const bf16x8*)&Qs[so_(wm+lr, ks*4+lq)];
      #pragma unroll
      for (int ni=0;ni<4;ni++) bfr[ni] = *(const bf16x8*)&Ks[so_(wn+ni*16+lr, ks*4+lq)];
      #pragma unroll
      for (int ni=0;ni<4;ni++)
        acc[ni] = __builtin_amdgcn_mfma_f32_16x16x32_bf16(af, bfr[ni], acc[ni], 0,0,0);
    }
    __syncthreads();
  }
  const float scale = 0.04419417382415922f;   // 1/sqrt(512)
  float rpart[4];
  #pragma unroll
  for (int r=0;r<4;r++) rpart[r]=0.f;
  #pragma unroll
  for (int ni=0;ni<4;ni++){
    int coll = wn + ni*16 + lr;
    int ch = coll>>3, off = coll&7;
    float av = a_s[coll];
    #pragma unroll
    for (int r=0;r<4;r++){
      int rowl = wm + lq*4 + r;
      int gi = i0 + rowl, gj = j0 + coll;
      float wv = 0.f;
      if (gj <= gi) wv = acc[ni][r]*scale*__expf(av-m_s[rowl]);
      smem[rowl*128 + (((ch) ^ (rowl&15))<<3) + off] = (short)f2bu(wv);
      rpart[r] += wv;
    }
  }
  __syncthreads();
  #pragma unroll
  for (int i=0;i<2;i++){
    int slot = i*512 + tid;
    int r = slot >> 4, c8 = slot & 15;
    uint4 val = *(const uint4*)&smem[eo_(r, c8)];
    *(uint4*)(W + ((size_t)h*S_ + i0 + r)*S_ + j0 + c8*8) = val;
  }
  #pragma unroll
  for (int r=0;r<4;r++){
    float v = rpart[r];
    v += __shfl_xor(v, 1, 16);
    v += __shfl_xor(v, 2, 16);
    v += __shfl_xor(v, 4, 16);
    v += __shfl_xor(v, 8, 16);
    if (lr == 0)
      atomicAdd(&rowsum[(size_t)h*S_ + i0 + wm + lq*4 + r], v);
  }
}

// ---------------- O = (W * inv_row) @ V  (causal k-range), inv fused ----------------
// 64-row i-tiles x 128-d tiles: grid 8*128; 512 threads = 8 waves.
__global__ __launch_bounds__(512) void pv_kernel(const bf16* __restrict__ W,
    const bf16* __restrict__ vT, const float* __restrict__ rowsum,
    const float* __restrict__ fl, bf16* __restrict__ O){
  int h = blockIdx.x & 7;
  int s = blockIdx.x >> 3;
  int ti = 31 - (s >> 2), tn = s & 3;
  int b = h >> 2, n = h & 3;
  int i0 = ti*64, d0 = tn*128;
  __shared__ __align__(16) short smem[2*12288];
  __shared__ float inv_s[64];
  int tid = threadIdx.x;
  if (tid < 64){
    size_t o = (size_t)h*S_ + i0 + tid;
    inv_s[tid] = 1.f/(fmaxf(fabsf(rowsum[o]), fl[o]) + EPS_CELL);
  }
  int w = tid>>6, l = tid&63, lq = l>>4, lr = l&15;
  int wm = (w>>1)*16, wn = (w&1)*64;
  const bf16* Wbase = W + ((size_t)h*S_ + i0)*S_;
  const bf16* Vbase = vT + ((size_t)h*DH_ + d0)*S_;
  floatx4 acc[4];
  #pragma unroll
  for (int ni=0;ni<4;ni++) acc[ni] = (floatx4){0.f,0.f,0.f,0.f};
  short* Ws0 = smem;          short* Vs0 = smem + 4096;
  short* Ws1 = smem + 12288;  short* Vs1 = smem + 16384;
  int NT = (i0 >> 6) + 1;
  STAGE_ASYNC5(Ws0, Wbase, S_, 0);
  STAGE_ASYNC5(Vs0, Vbase, S_, 0);
  STAGE_ASYNC5(Vs0, Vbase, S_, 1);
  __syncthreads();
  for (int tt=0; tt<NT; ++tt){
    short* Ws  = (tt&1) ? Ws1 : Ws0;
    short* Vs  = (tt&1) ? Vs1 : Vs0;
    short* Wsn = (tt&1) ? Ws0 : Ws1;
    short* Vsn = (tt&1) ? Vs0 : Vs1;
    if (tt+1 < NT){
      int j0 = (tt+1)*64;
      STAGE_ASYNC5(Wsn, Wbase + j0, S_, 0);
      STAGE_ASYNC5(Vsn, Vbase + j0, S_, 0);
      STAGE_ASYNC5(Vsn, Vbase + j0, S_, 1);
    }
    #pragma unroll
    for (int ks=0; ks<2; ks++){
      bf16x8 af, bfr[4];
      af = *(const bf16x8*)&Ws[so_(wm+lr, ks*4+lq)];
      #pragma unroll
      for (int ni=0;ni<4;ni++) bfr[ni] = *(const bf16x8*)&Vs[so_(wn+ni*16+lr, ks*4+lq)];
      #pragma unroll
      for (int ni=0;ni<4;ni++)
        acc[ni] = __builtin_amdgcn_mfma_f32_16x16x32_bf16(af, bfr[ni], acc[ni], 0,0,0);
    }
    __syncthreads();
  }
  #pragma unroll
  for (int ni=0;ni<4;ni++){
    int dl = wn + ni*16 + lr;
    int ch = dl>>3, off = dl&7;
    #pragma unroll
    for (int r=0;r<4;r++){
      int rowl = wm + lq*4 + r;
      smem[rowl*128 + (((ch) ^ (rowl&15))<<3) + off] = (short)f2bu(acc[ni][r] * inv_s[rowl]);
    }
  }
  __syncthreads();
  #pragma unroll
  for (int i=0;i<2;i++){
    int slot = i*512 + tid;
    int r = slot >> 4, c8 = slot & 15;
    uint4 val = *(const uint4*)&smem[eo_(r, c8)];
    *(uint4*)(O + (size_t)(b*S_ + i0 + r)*INNER_ + n*DH_ + d0 + c8*8) = val;
  }
}

// ---------------- fused: w_down transpose (512 blocks) | headnorm+gate (16384) ----
__global__ __launch_bounds__(256) void headnorm_wdown(const bf16* __restrict__ h,
    const float* __restrict__ onw, const float* __restrict__ skip,
    const bf16* __restrict__ xca, bf16* __restrict__ up,
    const float* __restrict__ w_down, bf16* __restrict__ w_down_t){
  __shared__ float sa[256], sb[256];
  __shared__ float tl[64][65];
  int bid = blockIdx.x, tid = threadIdx.x;
  if (bid < 512){
    int n0 = (bid & 15)*64, k0 = (bid >> 4)*64;
    transpose_tile(w_down, w_down_t, INNER_, E_, n0, k0, tid, tl);
    return;
  }
  int id = bid - 512;
  int n = id & 3; int bs = id >> 2;
  size_t hbase = (size_t)bs*INNER_ + n*DH_;
  float v0 = b2f(h[hbase+tid]);
  float v1 = b2f(h[hbase+256+tid]);
  sa[tid]=v0+v1; sb[tid]=v0*v0+v1*v1;
  __syncthreads();
  for (int off=128; off>0; off>>=1){
    if (tid<off){ sa[tid]+=sa[tid+off]; sb[tid]+=sb[tid+off]; }
    __syncthreads();
  }
  float mean = sa[0]*(1.f/DH_);
  float var  = sb[0]*(1.f/DH_) - mean*mean;
  float rstd = rsqrtf(var + LN_EPS_);
  #pragma unroll
  for (int e=0;e<2;e++){
    int dl = e*256+tid; int c = n*DH_+dl;
    float hv = e ? v1 : v0;
    float hn = (hv-mean)*rstd*onw[c];
    float hs = hn + skip[c]*b2f(xca[(size_t)bs*INNER_+c]);
    size_t zoff = (size_t)bs*(2*INNER_) + INNER_ + c;
    float zv = b2f(up[zoff]);
    float sz = zv/(1.f+expf(-zv));
    up[zoff] = f2b(hs*sz);
  }
}

extern "C" void kernel_launch(void* const* d_in, const int* in_sizes, int n_in,
                              void* d_out, int out_size, void* d_ws, size_t ws_size,
                              hipStream_t stream) {
  const float* x      = (const float*)d_in[0];
  const float* w_in   = (const float*)d_in[1];
  const float* b_in   = (const float*)d_in[2];
  const float* ln1_w  = (const float*)d_in[3];
  const float* w_up   = (const float*)d_in[4];
  const float* b_up   = (const float*)d_in[5];
  const float* conv_w = (const float*)d_in[6];
  const float* conv_b = (const float*)d_in[7];
  const float* q_w    = (const float*)d_in[8];
  const float* q_b    = (const float*)d_in[9];
  const float* k_w    = (const float*)d_in[10];
  const float* k_b    = (const float*)d_in[11];
  const float* v_w    = (const float*)d_in[12];
  const float* v_b    = (const float*)d_in[13];
  const float* ig_w   = (const float*)d_in[14];
  const float* ig_b   = (const float*)d_in[15];
  const float* fg_w   = (const float*)d_in[16];
  const float* fg_b   = (const float*)d_in[17];
  const float* onw    = (const float*)d_in[18];
  const float* skip   = (const float*)d_in[19];
  const float* w_down = (const float*)d_in[20];
  const float* b_down = (const float*)d_in[21];
  const float* post_w = (const float*)d_in[22];

  char* p = (char*)d_ws;
  auto alloc = [&](size_t bytes)->void*{ void* r = p; p += (bytes + 255) & ~(size_t)255; return r; };
  bf16* h_in = (bf16*)alloc((size_t)T_*E_*2);        // 8 MB
  bf16* xn   = (bf16*)alloc((size_t)T_*E_*2);        // 8 MB (reused as y later)
  bf16* up   = (bf16*)alloc((size_t)T_*2*INNER_*2);  // 32 MB (x_m | z)
  bf16* xca  = (bf16*)alloc((size_t)T_*INNER_*2);    // 16 MB
  bf16* qb_  = (bf16*)alloc((size_t)T_*INNER_*2);
  bf16* kb_  = (bf16*)alloc((size_t)T_*INNER_*2);
  bf16* vb_  = (bf16*)alloc((size_t)T_*INNER_*2);    // v; later attention O
  bf16* hb_  = (bf16*)alloc((size_t)T_*INNER_*2);    // reused as vT (h,d,s)
  float* igbuf = (float*)alloc((size_t)B_*NH_*S_*4);
  float* fgbuf = (float*)alloc((size_t)B_*NH_*S_*4);
  float* abuf  = (float*)alloc((size_t)B_*NH_*S_*4);
  float* Mbuf  = (float*)alloc((size_t)B_*NH_*S_*4);
  float* flbuf = (float*)alloc((size_t)B_*NH_*S_*4);
  float* rsbuf = (float*)alloc((size_t)B_*NH_*S_*4);
  bf16* gwb  = (bf16*)alloc((size_t)3*INNER_*8*2);   // 96 KB packed gate weights
  bf16* Wbuf = (bf16*)alloc((size_t)B_*NH_*S_*S_*2); // 67 MB decay-weighted scores
  bf16* ybuf = xn;
  bf16* vTb  = hb_;
  bf16* obuf = vb_;
  bf16* xbf    = Wbuf;                               // 4 MB, dead after GEMM1
  bf16* w_in_t = Wbuf + (size_t)T_*IN_;              // 1 MB, dead after GEMM1
  bf16* w_up_t = w_in_t + (size_t)E_*IN_;            // 8 MB, dead after GEMM2
  bf16* w_down_t = Wbuf;                             // written AFTER pv frees Wbuf

  // 0. fused prep: convert x, transpose w_in/w_up, pack gate weights
  prep_fused<<<2200, 256, 0, stream>>>(x, w_in, w_up, ig_w, fg_w,
      xbf, w_in_t, w_up_t, gwb);
  // 1. h_in = x @ w_in + b_in   (64x128 tiles: 512 blocks)
  mfma_gemm64<<<(T_/64)*(E_/128), 256, 0, stream>>>(xbf, w_in_t, b_in, h_in, IN_, IN_, E_, E_/128);
  // 2. xn = LN(h_in)*ln1_w
  ln_rows<bf16><<<T_, 256, 0, stream>>>(h_in, nullptr, ln1_w, xn);
  // 3. up = xn @ w_up + b_up   (128x128: 1024 blocks)
  mfma_gemm<<<(T_/128)*((2*INNER_)/128), 256, 0, stream>>>(xn, w_up_t, b_up, up, E_, E_, 2*INNER_, (2*INNER_)/128);
  // 4+5. fused conv+SiLU and q/k/v projections
  conv_headwise<<<T_/CTB_, 256, 0, stream>>>(up, conv_w, conv_b,
      q_w, q_b, k_w, k_b, v_w, v_b, xca, qb_, kb_, vb_);
  // 6+8. fused gates GEMV + v->vT transpose
  gates_transv<<<512 + 2048, 256, 0, stream>>>(qb_, kb_, vb_, gwb, ig_b, fg_b,
      igbuf, fgbuf, vTb);
  // 7. scans: a, M, floor; zero rowsums
  scan8<<<B_*NH_, 256, 0, stream>>>(igbuf, fgbuf, abuf, Mbuf, flbuf, rsbuf);
  // 9. W = QK^T * scale * decay (64x128 lower-triangle tiles, 8 waves/block), rowsums
  qk_decay_kernel<<<8*272, 512, 0, stream>>>(qb_, kb_, abuf, Mbuf, rsbuf, Wbuf);
  // 10. O = (W*inv) @ V -> obuf (8 waves/block)
  pv_kernel<<<8*128, 512, 0, stream>>>(Wbuf, vTb, rsbuf, flbuf, obuf);
  // 11. fused: w_down transpose (Wbuf now dead) + headnorm/skip/gate into z
  headnorm_wdown<<<512 + T_*NH_, 256, 0, stream>>>(obuf, onw, skip, xca, up,
      w_down, w_down_t);
  // 12. y = h_gated @ w_down + b_down   (64x128 tiles: 512 blocks)
  mfma_gemm64<<<(T_/64)*(E_/128), 256, 0, stream>>>(up + INNER_, w_down_t, b_down, ybuf, INNER_, 2*INNER_, E_, E_/128);
  // 13. out = LN(h_in + y)*post_w
  ln_rows<float><<<T_, 256, 0, stream>>>(h_in, ybuf, post_w, (float*)d_out);
}